// Round 12
// baseline (496.900 us; speedup 1.0000x reference)
//
#include <hip/hip_runtime.h>
#include <math.h>

#define BB 8
#define NN 12800
#define FF 256
#define DDIM 128
#define NBINS 100
#define BSIZE 128
#define NROT 50
#define NIDS 199
#define PTS (BB*NN)            // 102400

// ---- workspace layout (bytes) ----
#define OFF_OUT0 ((size_t)157286400)    // 52428800  : out0 bf16 [102400][256]
#define OFF_DMB  ((size_t)209715200)    // 26214400  : dm bf16 [800][128][128]
#define OFF_WB   ((size_t)235929600)    // 786432    : 6 weights bf16 transposed [256][256]
#define OFF_NORM ((size_t)236716032)    // 409600
#define OFF_MF   ((size_t)237125632)    // 409600
#define OFF_BIN  ((size_t)237535232)    // 409600 (int)
#define OFF_FLAT ((size_t)237944832)    // 409600 (int)
#define OFF_MSKI ((size_t)238354432)    // 409600 (int)
#define OFF_HIST ((size_t)238764032)    // 636800 (int)
#define OFF_OFFS ((size_t)239400832)    // 636800 (int)
#define OFF_FLAG ((size_t)240037632)    // 64
#define OFF_CNT  ((size_t)240037696)    // 64
#define OFF_LIST ((size_t)240037760)    // 409600 (int)
#define OFF_W1H  ((size_t)240447360)    // 65536 : w1^T hi bf16 [128][256]
#define OFF_W1L  ((size_t)240512896)    // 65536
#define OFF_W2H  ((size_t)240578432)    // 32768 : w2^T hi bf16 [128][128]
#define OFF_W2L  ((size_t)240611200)    // 32768
#define OFF_RH   ((size_t)240643968)    // 16384 : rot^T hi bf16 [64][128]
#define OFF_RL   ((size_t)240660352)    // 16384
#define HISTBYTES (8*100*199*4)

using short8  = __attribute__((ext_vector_type(8))) short;
using floatx4 = __attribute__((ext_vector_type(4))) float;

__device__ __forceinline__ ushort f2b(float f) {
    unsigned u = __float_as_uint(f);
    unsigned r = (u + 0x7FFFu + ((u >> 16) & 1u)) >> 16;
    return (ushort)r;
}
__device__ __forceinline__ float b2f(ushort h) {
    return __uint_as_float(((unsigned)h) << 16);
}
__device__ __forceinline__ uint4 pack8(const ushort* o) {
    uint4 u;
    u.x = (unsigned)o[0] | ((unsigned)o[1] << 16);
    u.y = (unsigned)o[2] | ((unsigned)o[3] << 16);
    u.z = (unsigned)o[4] | ((unsigned)o[5] << 16);
    u.w = (unsigned)o[6] | ((unsigned)o[7] << 16);
    return u;
}

// ---------- mask dtype sniffing ----------
__global__ void k_maskflag(const int* mi, int* flag) {
    __shared__ int notInt, notFloat;
    if (threadIdx.x == 0) { notInt = 0; notFloat = 0; }
    __syncthreads();
    int v = mi[threadIdx.x];
    if (v != 0 && v != 1) atomicOr(&notInt, 1);
    if (v != 0 && v != 0x3F800000) atomicOr(&notFloat, 1);
    __syncthreads();
    if (threadIdx.x == 0) flag[0] = (!notInt) ? 0 : ((!notFloat) ? 2 : 1);
}

__global__ void k_masknorm(const void* msk, const int* flag, int* mski) {
    int i = blockIdx.x * blockDim.x + threadIdx.x;
    if (i >= PTS) return;
    int f = flag[0];
    int v;
    if (f == 0)      v = ((const int*)msk)[i] != 0;
    else if (f == 2) v = ((const float*)msk)[i] != 0.0f;
    else             v = ((const unsigned char*)msk)[i] != 0;
    mski[i] = v;
}

// ---------- weight prep: fp32 [k][n] -> bf16 transposed [n][k] (GHConv weights) ----------
__global__ __launch_bounds__(256) void k_wprep(
    const float* s0, const float* s1, const float* s2,
    const float* s3, const float* s4, const float* s5,
    ushort* d0, ushort* d1, ushort* d2, ushort* d3, ushort* d4, ushort* d5)
{
    __shared__ float Ls[64 * 65];
    const float* src; ushort* dst;
    switch (blockIdx.y) {
        case 0: src = s0; dst = d0; break;
        case 1: src = s1; dst = d1; break;
        case 2: src = s2; dst = d2; break;
        case 3: src = s3; dst = d3; break;
        case 4: src = s4; dst = d4; break;
        default: src = s5; dst = d5; break;
    }
    int t = blockIdx.x;
    int kb = (t & 3) * 64, nb = (t >> 2) * 64;
    int tid = threadIdx.x;
    for (int q = 0; q < 4; ++q) {
        int g = q * 256 + tid;
        int kl = g >> 4, f4 = g & 15;
        float4 v = *(const float4*)(src + (size_t)(kb + kl) * 256 + nb + f4 * 4);
        Ls[kl * 65 + f4 * 4 + 0] = v.x;
        Ls[kl * 65 + f4 * 4 + 1] = v.y;
        Ls[kl * 65 + f4 * 4 + 2] = v.z;
        Ls[kl * 65 + f4 * 4 + 3] = v.w;
    }
    __syncthreads();
    for (int q = 0; q < 2; ++q) {
        int g = q * 256 + tid;
        int nl = g >> 3, wg = g & 7;
        ushort o[8];
        #pragma unroll
        for (int c = 0; c < 8; ++c) o[c] = f2b(Ls[(wg * 8 + c) * 65 + nl]);
        *(uint4*)(dst + (size_t)(nb + nl) * 256 + kb + wg * 8) = pack8(o);
    }
}

// ---------- split-weight prep: fp32 [K][srcN] -> hi/lo bf16 transposed [N][K] ----------
__global__ __launch_bounds__(256) void k_wsplit(const float* __restrict__ src, int K, int N,
                                               int srcN, int nvalid,
                                               ushort* __restrict__ dh, ushort* __restrict__ dl) {
    __shared__ float Ls[64 * 65];
    int tilesN = N >> 6;
    int kb = (blockIdx.x / tilesN) * 64, nb = (blockIdx.x % tilesN) * 64;
    int tid = threadIdx.x;
    for (int q = 0; q < 4; ++q) {
        int g = q * 256 + tid;
        int kl = g >> 4, c4 = (g & 15) * 4;
        #pragma unroll
        for (int j = 0; j < 4; ++j) {
            int n = nb + c4 + j;
            float v = (n < nvalid) ? src[(size_t)(kb + kl) * srcN + n] : 0.f;
            Ls[kl * 65 + c4 + j] = v;
        }
    }
    __syncthreads();
    for (int q = 0; q < 2; ++q) {
        int g = q * 256 + tid;
        int nl = g >> 3, wg = g & 7;
        ushort oh[8], ol[8];
        #pragma unroll
        for (int c = 0; c < 8; ++c) {
            float v = Ls[(wg * 8 + c) * 65 + nl];
            ushort h = f2b(v);
            oh[c] = h;
            ol[c] = f2b(v - b2f(h));
        }
        *(uint4*)(dh + (size_t)(nb + nl) * K + kb + wg * 8) = pack8(oh);
        *(uint4*)(dl + (size_t)(nb + nl) * K + kb + wg * 8) = pack8(ol);
    }
}

// ---------- MFMA LDS helpers (layout verified in rounds 2-11) ----------
// async staging: linear LDS dest (wave-uniform base + lane*16) with the XOR
// swizzle folded into the per-lane GLOBAL source chunk (involution: dst = src^(row&7)).
__device__ __forceinline__ void stage_async(const ushort* __restrict__ src, size_t pitch,
                                            const int* __restrict__ rowmap, int rowbase, size_t kbase,
                                            ushort* lds, int nrows, int tid) {
    int lane = tid & 63, wid = tid >> 6;
    int total = nrows * 8;
    for (int b0 = 0; b0 < total; b0 += 512) {
        int g = b0 + wid * 64 + lane;
        int row = g >> 3;
        int ck = (g & 7) ^ (row & 7);
        size_t srow = rowmap ? (size_t)rowmap[rowbase + row] : (size_t)(rowbase + row);
        const ushort* gp = src + srow * pitch + kbase + ck * 8;
        ushort* lp = lds + (size_t)(b0 + wid * 64) * 8;   // wave-uniform
        __builtin_amdgcn_global_load_lds(
            (const __attribute__((address_space(1))) unsigned int*)gp,
            (__attribute__((address_space(3))) unsigned int*)lp, 16, 0, 0);
    }
}

__device__ __forceinline__ short8 frag_ld(const ushort* lds, int row, int kc, int lane) {
    int w0 = (kc * 16 + ((lane >> 4) << 2)) ^ ((row & 7) << 2);
    return *(const short8*)((const char*)lds + row * 128 + w0 * 4);
}

// direct global B-fragment load (weights are L2-resident, no swizzle needed)
__device__ __forceinline__ short8 bfrag_g(const ushort* __restrict__ W, int Kpitch,
                                          int row, int k0) {
    return *(const short8*)(W + (size_t)row * Kpitch + k0);
}

// ---------- stage 1 v5: fused LN + FFN + rot; weights streamed from L2 into VGPRs ----------
// 32 points/block, 512 threads, 32KB LDS, <=64 VGPR -> 4 blocks/CU, ~7 barriers total.
__global__ __launch_bounds__(512, 8) void k_stage1(
    const float* __restrict__ x, const float* __restrict__ g, const float* __restrict__ be,
    const float* __restrict__ b1, const float* __restrict__ b2,
    const ushort* __restrict__ w1h, const ushort* __restrict__ w1l,
    const ushort* __restrict__ w2h, const ushort* __restrict__ w2l,
    const ushort* __restrict__ rth, const ushort* __restrict__ rtl,
    const int* __restrict__ mski,
    ushort* __restrict__ xn_out, ushort* __restrict__ xdh_out, ushort* __restrict__ xdl_out,
    int* __restrict__ bin_out, int* __restrict__ fixlist, int* __restrict__ fixcnt)
{
    __shared__ ushort lXh[4 * 2048];   // 16KB : 4 k-slabs x [32 rows][64 k]
    __shared__ ushort lXl[4 * 2048];   // 16KB
    int tid = threadIdx.x, lane = tid & 63, wid = tid >> 6;
    int base = blockIdx.x * 32;
    int l15 = lane & 15;
    int r4 = (lane >> 4) * 4;
    int kf = (lane >> 4) * 8;          // per-lane k offset within a 32-k fragment

    {   // ---- phase 0: LN (16 threads/point, 16 features each) ----
        int row = tid >> 4, sub = tid & 15;
        const float* xr = x + (size_t)(base + row) * FF + sub * 16;
        float v[16];
        float s = 0.f;
        #pragma unroll
        for (int q = 0; q < 4; ++q) {
            float4 f = *(const float4*)(xr + q * 4);
            v[q*4+0] = f.x; v[q*4+1] = f.y; v[q*4+2] = f.z; v[q*4+3] = f.w;
            s += f.x + f.y + f.z + f.w;
        }
        s += __shfl_xor(s, 1, 16); s += __shfl_xor(s, 2, 16);
        s += __shfl_xor(s, 4, 16); s += __shfl_xor(s, 8, 16);
        float mu = s * (1.f / 256.f);
        float s2 = 0.f;
        #pragma unroll
        for (int q = 0; q < 16; ++q) { float d = v[q] - mu; s2 += d * d; }
        s2 += __shfl_xor(s2, 1, 16); s2 += __shfl_xor(s2, 2, 16);
        s2 += __shfl_xor(s2, 4, 16); s2 += __shfl_xor(s2, 8, 16);
        float rs = 1.0f / sqrtf(s2 * (1.f / 256.f) + 1e-6f);
        ushort* xo = xn_out + (size_t)(base + row) * FF + sub * 16;
        #pragma unroll
        for (int j = 0; j < 2; ++j) {
            int i0 = sub * 16 + j * 8;
            float4 g0 = *(const float4*)(g + i0);
            float4 g1 = *(const float4*)(g + i0 + 4);
            float4 e0 = *(const float4*)(be + i0);
            float4 e1 = *(const float4*)(be + i0 + 4);
            float gv[8] = {g0.x,g0.y,g0.z,g0.w,g1.x,g1.y,g1.z,g1.w};
            float ev[8] = {e0.x,e0.y,e0.z,e0.w,e1.x,e1.y,e1.z,e1.w};
            ushort hh[8], ll[8];
            #pragma unroll
            for (int c = 0; c < 8; ++c) {
                float xv = (v[j*8+c] - mu) * rs * gv[c] + ev[c];
                ushort h = f2b(xv);
                hh[c] = h;
                ll[c] = f2b(xv - b2f(h));
            }
            uint4 uh = pack8(hh), ul = pack8(ll);
            *(uint4*)(xo + j * 8) = uh;
            int kb = i0 >> 6;
            int wg = (i0 & 63) >> 3;
            int w0 = (wg * 4) ^ ((row & 7) << 2);
            *(uint4*)((char*)lXh + kb * 4096 + row * 128 + w0 * 4) = uh;
            *(uint4*)((char*)lXl + kb * 4096 + row * 128 + w0 * 4) = ul;
        }
    }
    __syncthreads();   // xn visible

    int mg = wid >> 2, ng = wid & 3;
    int wm = mg * 16, wn = ng * 32;
    floatx4 zf = {0.f, 0.f, 0.f, 0.f};

    // ---- GEMM1: h = elu(xn @ w1 + b1), M=32 N=128 K=256, B streamed from L2 ----
    floatx4 acc[2];
    acc[0] = zf; acc[1] = zf;
    for (int kb = 0; kb < 4; ++kb) {
        #pragma unroll
        for (int kc = 0; kc < 2; ++kc) {
            int k0 = kb * 64 + kc * 32 + kf;
            short8 ah = frag_ld(lXh + kb * 2048, wm + l15, kc, lane);
            short8 al = frag_ld(lXl + kb * 2048, wm + l15, kc, lane);
            #pragma unroll
            for (int n = 0; n < 2; n++) {
                int rowb = wn + n * 16 + l15;
                short8 bh = bfrag_g(w1h, 256, rowb, k0);
                short8 bl = bfrag_g(w1l, 256, rowb, k0);
                acc[n] = __builtin_amdgcn_mfma_f32_16x16x32_bf16(ah, bh, acc[n], 0, 0, 0);
                acc[n] = __builtin_amdgcn_mfma_f32_16x16x32_bf16(ah, bl, acc[n], 0, 0, 0);
                acc[n] = __builtin_amdgcn_mfma_f32_16x16x32_bf16(al, bh, acc[n], 0, 0, 0);
            }
        }
    }
    __syncthreads();   // GEMM1 reads of lX done
    {   // ep1: h -> lX slabs 0-1
        #pragma unroll
        for (int n = 0; n < 2; n++) {
            int cg = wn + n * 16 + l15;
            float b1v = b1[cg];
            int slab = cg >> 6, c64 = cg & 63;
            int wg = c64 >> 3, e = c64 & 7;
            #pragma unroll
            for (int i = 0; i < 4; i++) {
                int r = wm + r4 + i;
                float hv = acc[n][i] + b1v;
                hv = (hv > 0.f) ? hv : expm1f(hv);
                ushort h = f2b(hv);
                int w0 = (wg * 4) ^ ((r & 7) << 2);
                int idx = slab * 2048 + r * 64 + w0 * 2 + e;
                lXh[idx] = h;
                lXl[idx] = f2b(hv - b2f(h));
            }
        }
    }
    __syncthreads();   // h visible

    // ---- GEMM2: xd = h @ w2 + b2, M=32 N=128 K=128 ----
    floatx4 acc2[2];
    acc2[0] = zf; acc2[1] = zf;
    for (int kb = 0; kb < 2; ++kb) {
        #pragma unroll
        for (int kc = 0; kc < 2; ++kc) {
            int k0 = kb * 64 + kc * 32 + kf;
            short8 ah = frag_ld(lXh + kb * 2048, wm + l15, kc, lane);
            short8 al = frag_ld(lXl + kb * 2048, wm + l15, kc, lane);
            #pragma unroll
            for (int n = 0; n < 2; n++) {
                int rowb = wn + n * 16 + l15;
                short8 bh = bfrag_g(w2h, 128, rowb, k0);
                short8 bl = bfrag_g(w2l, 128, rowb, k0);
                acc2[n] = __builtin_amdgcn_mfma_f32_16x16x32_bf16(ah, bh, acc2[n], 0, 0, 0);
                acc2[n] = __builtin_amdgcn_mfma_f32_16x16x32_bf16(ah, bl, acc2[n], 0, 0, 0);
                acc2[n] = __builtin_amdgcn_mfma_f32_16x16x32_bf16(al, bh, acc2[n], 0, 0, 0);
            }
        }
    }
    __syncthreads();   // GEMM2 reads done (slabs 2-3 free)
    {   // ep2: xd -> global hi/lo + lX slabs 2-3
        #pragma unroll
        for (int n = 0; n < 2; n++) {
            int cg = wn + n * 16 + l15;
            float b2v = b2[cg];
            int slab = 2 + (cg >> 6), c64 = cg & 63;
            int wg = c64 >> 3, e = c64 & 7;
            #pragma unroll
            for (int i = 0; i < 4; i++) {
                int r = wm + r4 + i;
                float xv = acc2[n][i] + b2v;
                ushort h = f2b(xv);
                ushort lo = f2b(xv - b2f(h));
                size_t go = (size_t)(base + r) * DDIM + cg;
                xdh_out[go] = h;
                xdl_out[go] = lo;
                int w0 = (wg * 4) ^ ((r & 7) << 2);
                int idx = slab * 2048 + r * 64 + w0 * 2 + e;
                lXh[idx] = h;
                lXl[idx] = lo;
            }
        }
    }
    __syncthreads();   // xd visible

    // ---- GEMM3: mul = xd @ rot, M=32 N=64 K=128 ----
    floatx4 acc3 = zf;
    int wn3 = ng * 16;
    for (int kb = 0; kb < 2; ++kb) {
        #pragma unroll
        for (int kc = 0; kc < 2; ++kc) {
            int k0 = kb * 64 + kc * 32 + kf;
            short8 ah = frag_ld(lXh + (2 + kb) * 2048, wm + l15, kc, lane);
            short8 al = frag_ld(lXl + (2 + kb) * 2048, wm + l15, kc, lane);
            int rowb = wn3 + l15;
            short8 bh = bfrag_g(rth, 128, rowb, k0);
            short8 bl = bfrag_g(rtl, 128, rowb, k0);
            acc3 = __builtin_amdgcn_mfma_f32_16x16x32_bf16(ah, bh, acc3, 0, 0, 0);
            acc3 = __builtin_amdgcn_mfma_f32_16x16x32_bf16(ah, bl, acc3, 0, 0, 0);
            acc3 = __builtin_amdgcn_mfma_f32_16x16x32_bf16(al, bh, acc3, 0, 0, 0);
        }
    }
    __syncthreads();   // GEMM3 + GEMM2 reads of slabs 0-1 done -> lMul overwrite safe
    float* lMul = (float*)lXh;
    {
        #pragma unroll
        for (int i = 0; i < 4; i++) {
            int r = wm + r4 + i;
            lMul[r * 65 + wn3 + l15] = acc3[i];
        }
    }
    __syncthreads();

    {   // ---- top-2 argmax over [mul, -mul], margin flag (16 thr/pt) ----
        int p = tid >> 4, q = tid & 15;
        float v1 = -1e30f, v2 = -1e30f; int i1 = 1 << 29;
        #pragma unroll
        for (int j = 0; j < 4; ++j) {
            int c = q * 4 + j;
            if (c < 50) {
                float m = lMul[p * 65 + c];
                float wv, lv; int wi, li;
                if (m >= 0.f) { wv = m; wi = c; lv = -m; li = 50 + c; }
                else          { wv = -m; wi = 50 + c; lv = m; li = c; }
                if (wv > v1 || (wv == v1 && wi < i1)) { v2 = v1; v1 = wv; i1 = wi; }
                else if (wv > v2) v2 = wv;
                if (lv > v1 || (lv == v1 && li < i1)) { v2 = v1; v1 = lv; i1 = li; }
                else if (lv > v2) v2 = lv;
            }
        }
        #pragma unroll
        for (int off = 1; off < 16; off <<= 1) {
            float o1 = __shfl_xor(v1, off, 16);
            int   oi = __shfl_xor(i1, off, 16);
            float o2 = __shfl_xor(v2, off, 16);
            bool take = (o1 > v1) || (o1 == v1 && oi < i1);
            float small = take ? v1 : o1;
            if (take) { v1 = o1; i1 = oi; }
            v2 = fmaxf(fmaxf(v2, o2), small);
        }
        if (q == 0) {
            int pt = base + p;
            bin_out[pt] = i1 + (mski[pt] ? 0 : (NBINS - 1));
            float tau = 3e-4f + 1.5e-3f * v1;
            if (v1 - v2 < tau) {
                int pos = atomicAdd(fixcnt, 1);
                fixlist[pos] = pt;
            }
        }
    }
}

// ---------- fp64 fixup for margin-flagged points ----------
__global__ __launch_bounds__(64) void k_fixup(
    const float* __restrict__ x, const float* __restrict__ g, const float* __restrict__ be,
    const float* __restrict__ w1, const float* __restrict__ b1,
    const float* __restrict__ w2, const float* __restrict__ b2,
    const float* __restrict__ rot, const int* __restrict__ mski,
    const int* __restrict__ fixlist, const int* __restrict__ fixcnt,
    int* __restrict__ bin_out)
{
    __shared__ double xn_s[256];
    __shared__ double h_s[128];
    __shared__ double xd_s[128];
    int lane = threadIdx.x;
    int n = fixcnt[0];
    for (int e = blockIdx.x; e < n; e += gridDim.x) {
        int pt = fixlist[e];
        const float* xr = x + (size_t)pt * FF;
        double s = 0.0, xv[4];
        #pragma unroll
        for (int q = 0; q < 4; q++) { xv[q] = (double)xr[lane + q * 64]; s += xv[q]; }
        #pragma unroll
        for (int off = 1; off < 64; off <<= 1) s += __shfl_xor(s, off, 64);
        double mu = s * (1.0 / 256.0);
        double s2 = 0.0;
        #pragma unroll
        for (int q = 0; q < 4; q++) { double d = xv[q] - mu; s2 += d * d; }
        #pragma unroll
        for (int off = 1; off < 64; off <<= 1) s2 += __shfl_xor(s2, off, 64);
        double rs = 1.0 / sqrt(s2 * (1.0 / 256.0) + 1e-6);
        #pragma unroll
        for (int q = 0; q < 4; q++) {
            int i = lane + q * 64;
            xn_s[i] = (xv[q] - mu) * rs * (double)g[i] + (double)be[i];
        }
        __syncthreads();
        #pragma unroll
        for (int q = 0; q < 2; q++) {
            int j = lane + q * 64;
            double a0 = 0.0, a1 = 0.0;
            for (int k = 0; k < FF; k += 2) {
                a0 += xn_s[k] * (double)w1[k * DDIM + j];
                a1 += xn_s[k + 1] * (double)w1[(k + 1) * DDIM + j];
            }
            double a = (double)b1[j] + a0 + a1;
            h_s[j] = (a > 0.0) ? a : expm1(a);
        }
        __syncthreads();
        #pragma unroll
        for (int q = 0; q < 2; q++) {
            int j = lane + q * 64;
            double a0 = 0.0, a1 = 0.0;
            for (int k = 0; k < DDIM; k += 2) {
                a0 += h_s[k] * (double)w2[k * DDIM + j];
                a1 += h_s[k + 1] * (double)w2[(k + 1) * DDIM + j];
            }
            xd_s[j] = (double)b2[j] + a0 + a1;
        }
        __syncthreads();
        double v; int idx;
        if (lane < NROT) {
            double m = 0.0;
            for (int k = 0; k < DDIM; k++) m += xd_s[k] * (double)rot[k * 100 + lane];
            if (m >= 0.0) { v = m; idx = lane; } else { v = -m; idx = 50 + lane; }
        } else { v = -1e300; idx = 1 << 29; }
        #pragma unroll
        for (int off = 1; off < 64; off <<= 1) {
            double ov = __shfl_xor(v, off, 64);
            int oi = __shfl_xor(idx, off, 64);
            if (ov > v || (ov == v && oi < idx)) { v = ov; idx = oi; }
        }
        if (lane == 0) bin_out[pt] = idx + (mski[pt] ? 0 : (NBINS - 1));
        __syncthreads();
    }
}

// ---------- binning: stable counting sort ----------
__global__ void k_count(const int* __restrict__ bin, int* __restrict__ hist) {
    int c = blockIdx.x % 100, b = blockIdx.x / 100;
    int t = threadIdx.x;
    int v = bin[b * NN + c * BSIZE + t];
    atomicAdd(&hist[(b * 100 + c) * NIDS + v], 1);
}

__global__ void k_offsets(const int* __restrict__ hist, int* __restrict__ offs) {
    __shared__ int tot[NIDS];
    __shared__ int start[NIDS];
    int b = blockIdx.x, v = threadIdx.x;
    if (v < NIDS) {
        int s = 0;
        for (int c = 0; c < 100; c++) s += hist[(b * 100 + c) * NIDS + v];
        tot[v] = s;
    }
    __syncthreads();
    if (threadIdx.x == 0) {
        int run = 0;
        for (int i = 0; i < NIDS; i++) { start[i] = run; run += tot[i]; }
    }
    __syncthreads();
    if (v < NIDS) {
        int run = start[v];
        for (int c = 0; c < 100; c++) {
            offs[(b * 100 + c) * NIDS + v] = run;
            run += hist[(b * 100 + c) * NIDS + v];
        }
    }
}

__global__ void k_scatter(const int* __restrict__ bin, const int* __restrict__ offs,
                          const int* __restrict__ mski, int* __restrict__ flat,
                          float* __restrict__ mf) {
    __shared__ int sv[BSIZE];
    int c = blockIdx.x % 100, b = blockIdx.x / 100;
    int t = threadIdx.x;
    int n = c * BSIZE + t;
    int v = bin[b * NN + n];
    sv[t] = v;
    __syncthreads();
    int rank = 0;
    for (int u = 0; u < t; u++) rank += (sv[u] == v);
    int r = offs[(b * 100 + c) * NIDS + v] + rank;
    flat[b * NN + r] = b * NN + n;
    mf[b * NN + r] = mski[b * NN + n] ? 1.0f : 0.0f;
}

// ---------- k_dm v2: per-bin Gram matrix via split-bf16 MFMA, async gather staging ----------
__global__ __launch_bounds__(512, 4) void k_dm(const ushort* __restrict__ xdh, const ushort* __restrict__ xdl,
                                               const int* __restrict__ flat, const float* __restrict__ mf,
                                               ushort* __restrict__ dmb, float* __restrict__ norm) {
    __shared__ ushort lX[32768];   // Xh slabs at [0),[8192); Xl at [16384),[24576); bounce aliases [0..17408)
    __shared__ float na[128];
    __shared__ float ml[128];
    __shared__ float ps[512];
    int tid = threadIdx.x, lane = tid & 63, wid = tid >> 6;
    int g = blockIdx.x;
    int rowbase = g * 128;
    int l15 = lane & 15;
    int r4 = (lane >> 4) * 4;
    int mg = wid >> 2, ng = wid & 3;
    int wm = mg * 64, wn = ng * 32;
    floatx4 zf = {0.f, 0.f, 0.f, 0.f};

    stage_async(xdh, 128, flat, rowbase, 0, lX, 128, tid);
    stage_async(xdh, 128, flat, rowbase, 64, lX + 8192, 128, tid);
    stage_async(xdl, 128, flat, rowbase, 0, lX + 16384, 128, tid);
    stage_async(xdl, 128, flat, rowbase, 64, lX + 24576, 128, tid);
    if (tid < 128) ml[tid] = mf[rowbase + tid];
    __syncthreads();

    {   // na pass
        int row = tid >> 2, part = tid & 3;
        float s = 0.f;
        #pragma unroll
        for (int kb = 0; kb < 2; ++kb) {
            const ushort* ph = lX + kb * 8192 + row * 64 + part * 16;
            #pragma unroll
            for (int q = 0; q < 2; ++q) {
                uint4 uh = *(const uint4*)(ph + q * 8);
                uint4 ul = *(const uint4*)(ph + 16384 + q * 8);
                const unsigned* wh_ = (const unsigned*)&uh;
                const unsigned* wl_ = (const unsigned*)&ul;
                #pragma unroll
                for (int w = 0; w < 4; ++w) {
                    float x0 = b2f((ushort)(wh_[w] & 0xFFFFu)) + b2f((ushort)(wl_[w] & 0xFFFFu));
                    float x1 = b2f((ushort)(wh_[w] >> 16)) + b2f((ushort)(wl_[w] >> 16));
                    s = fmaf(x0, x0, s);
                    s = fmaf(x1, x1, s);
                }
            }
        }
        s += __shfl_xor(s, 1, 4);
        s += __shfl_xor(s, 2, 4);
        if (part == 0) na[row] = s;
    }

    floatx4 acc[4][2];
    #pragma unroll
    for (int m = 0; m < 4; m++) { acc[m][0] = zf; acc[m][1] = zf; }
    for (int kb = 0; kb < 2; ++kb) {
        #pragma unroll
        for (int kc = 0; kc < 2; ++kc) {
            short8 ah[4], al[4], bh[2], bl[2];
            #pragma unroll
            for (int m = 0; m < 4; m++) {
                ah[m] = frag_ld(lX + kb * 8192, wm + m * 16 + l15, kc, lane);
                al[m] = frag_ld(lX + 16384 + kb * 8192, wm + m * 16 + l15, kc, lane);
            }
            #pragma unroll
            for (int n = 0; n < 2; n++) {
                bh[n] = frag_ld(lX + kb * 8192, wn + n * 16 + l15, kc, lane);
                bl[n] = frag_ld(lX + 16384 + kb * 8192, wn + n * 16 + l15, kc, lane);
            }
            #pragma unroll
            for (int m = 0; m < 4; m++)
                #pragma unroll
                for (int n = 0; n < 2; n++) {
                    acc[m][n] = __builtin_amdgcn_mfma_f32_16x16x32_bf16(ah[m], bh[n], acc[m][n], 0, 0, 0);
                    acc[m][n] = __builtin_amdgcn_mfma_f32_16x16x32_bf16(ah[m], bl[n], acc[m][n], 0, 0, 0);
                    acc[m][n] = __builtin_amdgcn_mfma_f32_16x16x32_bf16(al[m], bh[n], acc[m][n], 0, 0, 0);
                }
        }
    }
    __syncthreads();

    ushort* Ls = lX;
    for (int m = 0; m < 4; ++m) {
        int r0 = wm + m * 16 + r4;
        float rs[4] = {0.f, 0.f, 0.f, 0.f};
        #pragma unroll
        for (int n = 0; n < 2; ++n) {
            int c = wn + n * 16 + l15;
            float nac = na[c], mlc = ml[c];
            #pragma unroll
            for (int i = 0; i < 4; ++i) {
                int r = r0 + i;
                float D2 = na[r] - 2.f * acc[m][n][i] + nac;
                float dv = expf(-0.1f * sqrtf(fmaxf(D2, 1e-6f)));
                dv *= ml[r] * mlc;
                rs[i] += dv;
                Ls[r * 136 + c] = f2b(dv);
            }
        }
        #pragma unroll
        for (int off = 1; off < 16; off <<= 1) {
            #pragma unroll
            for (int i = 0; i < 4; ++i) rs[i] += __shfl_xor(rs[i], off, 16);
        }
        if (l15 == 0) {
            #pragma unroll
            for (int i = 0; i < 4; ++i) ps[(r0 + i) * 4 + ng] = rs[i];
        }
    }
    __syncthreads();

    #pragma unroll
    for (int it = 0; it < 4; ++it) {
        int gi = it * 512 + tid;
        int row = gi >> 4, ch = gi & 15;
        uint4 v = *(const uint4*)(Ls + row * 136 + ch * 8);
        *(uint4*)(dmb + (size_t)g * 16384 + row * 128 + ch * 8) = v;
    }
    if (tid < 128) {
        float deg = ps[tid * 4 + 0] + ps[tid * 4 + 1] + ps[tid * 4 + 2] + ps[tid * 4 + 3];
        deg = fminf(deg, 1000.0f);
        norm[rowbase + tid] = (1.0f / sqrtf(deg + 1e-6f)) * ml[tid];
    }
}

// ---------- fused per-layer graph conv v2: merged triple GEMM, 80KB LDS, 2 blocks/CU ----------
// 1-D grid 3200 with XCD-locality remap.
template<int LAYER>
__global__ __launch_bounds__(512, 4) void k_layer(
    const ushort* __restrict__ A, const int* __restrict__ rowmap,
    const ushort* __restrict__ ThT, const ushort* __restrict__ WhT, const ushort* __restrict__ WtT,
    const float* __restrict__ bt, const ushort* __restrict__ dmb,
    const float* __restrict__ norm, const float* __restrict__ mf,
    ushort* __restrict__ outb, float* __restrict__ outf, const int* __restrict__ flatscat)
{
    __shared__ char smem[81920];
    ushort* lAbuf = (ushort*)smem;                 // 2 x 16KB A ping
    ushort* lB    = (ushort*)(smem + 32768);       // 6 x 8KB: th0 th1 wh0 wh1 wt0 wt1
    ushort* lT    = (ushort*)smem;                 // post-GEMM: 2 x 8KB T^T j-slabs
    ushort* ldm   = (ushort*)(smem + 32768);       // post-GEMM: 2 x 16KB dm slabs

    int tid = threadIdx.x, lane = tid & 63, wid = tid >> 6;
    int bid = blockIdx.x;
    int grp = bid >> 5, within = bid & 31;
    int nh = within >> 3, g = grp * 8 + (within & 7);
    int rowbase = g * 128, nbase = nh * 64;
    int l15 = lane & 15;
    int r4 = (lane >> 4) * 4;
    int wm = (wid >> 1) * 32, wn = (wid & 1) * 32;
    const ushort* dmg = dmb + (size_t)g * 16384;
    floatx4 zf = {0.f, 0.f, 0.f, 0.f};

    stage_async(A, 256, rowmap, rowbase, 0, lAbuf, 128, tid);
    stage_async(ThT, 256, nullptr, nbase, 0, lB + 0 * 4096, 64, tid);
    stage_async(WhT, 256, nullptr, nbase, 0, lB + 2 * 4096, 64, tid);
    stage_async(WtT, 256, nullptr, nbase, 0, lB + 4 * 4096, 64, tid);
    __syncthreads();

    floatx4 accT[2][2], accH[2][2], accG[2][2];
    #pragma unroll
    for (int m = 0; m < 2; m++)
        #pragma unroll
        for (int n = 0; n < 2; n++) { accT[m][n] = zf; accH[m][n] = zf; accG[m][n] = zf; }
    for (int kb = 0; kb < 4; ++kb) {
        if (kb < 3) {
            int pp = (kb + 1) & 1;
            stage_async(A, 256, rowmap, rowbase, (size_t)(kb + 1) * 64, lAbuf + pp * 8192, 128, tid);
            stage_async(ThT, 256, nullptr, nbase, (size_t)(kb + 1) * 64, lB + (0 + pp) * 4096, 64, tid);
            stage_async(WhT, 256, nullptr, nbase, (size_t)(kb + 1) * 64, lB + (2 + pp) * 4096, 64, tid);
            stage_async(WtT, 256, nullptr, nbase, (size_t)(kb + 1) * 64, lB + (4 + pp) * 4096, 64, tid);
        }
        const ushort* lA = lAbuf + (kb & 1) * 8192;
        const ushort* sTh = lB + (0 + (kb & 1)) * 4096;
        const ushort* sWh = lB + (2 + (kb & 1)) * 4096;
        const ushort* sWt = lB + (4 + (kb & 1)) * 4096;
        #pragma unroll
        for (int kc = 0; kc < 2; ++kc) {
            short8 a[2], bt_[2], bh_[2], bg_[2];
            #pragma unroll
            for (int m = 0; m < 2; m++) a[m] = frag_ld(lA, wm + m * 16 + l15, kc, lane);
            #pragma unroll
            for (int n = 0; n < 2; n++) {
                bt_[n] = frag_ld(sTh, wn + n * 16 + l15, kc, lane);
                bh_[n] = frag_ld(sWh, wn + n * 16 + l15, kc, lane);
                bg_[n] = frag_ld(sWt, wn + n * 16 + l15, kc, lane);
            }
            #pragma unroll
            for (int m = 0; m < 2; m++)
                #pragma unroll
                for (int n = 0; n < 2; n++) {
                    accT[m][n] = __builtin_amdgcn_mfma_f32_16x16x32_bf16(a[m], bt_[n], accT[m][n], 0, 0, 0);
                    accH[m][n] = __builtin_amdgcn_mfma_f32_16x16x32_bf16(a[m], bh_[n], accH[m][n], 0, 0, 0);
                    accG[m][n] = __builtin_amdgcn_mfma_f32_16x16x32_bf16(a[m], bg_[n], accG[m][n], 0, 0, 0);
                }
        }
        __syncthreads();
    }

    stage_async(dmg, 128, nullptr, 0, 0, ldm, 128, tid);
    stage_async(dmg, 128, nullptr, 0, 64, ldm + 8192, 128, tid);

    {   // T^T (scaled by norm, bf16, frag-swizzled) into lT j-slabs
        #pragma unroll
        for (int m = 0; m < 2; m++) {
            float4 nv = *(const float4*)(norm + rowbase + wm + m * 16 + r4);
            float nvv[4] = {nv.x, nv.y, nv.z, nv.w};
            int jloc0 = wm + m * 16 + r4;
            int jb = jloc0 >> 6, jj = jloc0 & 63;
            #pragma unroll
            for (int n = 0; n < 2; n++) {
                int cloc = wn + n * 16 + l15;
                char* bp = (char*)(lT + jb * 4096) + cloc * 128;
                int cx = (cloc & 7) << 2;
                ushort t0 = f2b(accT[m][n][0] * nvv[0]);
                ushort t1 = f2b(accT[m][n][1] * nvv[1]);
                ushort t2 = f2b(accT[m][n][2] * nvv[2]);
                ushort t3 = f2b(accT[m][n][3] * nvv[3]);
                *(unsigned*)(bp + ((((jj >> 1) + 0) ^ cx) << 2)) = (unsigned)t0 | ((unsigned)t1 << 16);
                *(unsigned*)(bp + ((((jj >> 1) + 1) ^ cx) << 2)) = (unsigned)t2 | ((unsigned)t3 << 16);
            }
        }
    }
    __syncthreads();

    floatx4 accFH[2][2];
    #pragma unroll
    for (int m = 0; m < 2; m++) { accFH[m][0] = zf; accFH[m][1] = zf; }
    for (int kb = 0; kb < 2; ++kb) {
        #pragma unroll
        for (int kc = 0; kc < 2; ++kc) {
            short8 a[2], b[2];
            #pragma unroll
            for (int m = 0; m < 2; m++) a[m] = frag_ld(ldm + kb * 8192, wm + m * 16 + l15, kc, lane);
            #pragma unroll
            for (int n = 0; n < 2; n++) b[n] = frag_ld(lT + kb * 4096, wn + n * 16 + l15, kc, lane);
            #pragma unroll
            for (int m = 0; m < 2; m++)
                #pragma unroll
                for (int n = 0; n < 2; n++)
                    accFH[m][n] = __builtin_amdgcn_mfma_f32_16x16x32_bf16(a[m], b[n], accFH[m][n], 0, 0, 0);
        }
    }
    __syncthreads();

    for (int m = 0; m < 2; m++) {
        int r0l = wm + m * 16 + r4;
        int r0g = rowbase + r0l;
        float4 mv = *(const float4*)(mf + r0g);
        float4 nv = *(const float4*)(norm + r0g);
        float mvv[4] = {mv.x, mv.y, mv.z, mv.w};
        float nvv[4] = {nv.x, nv.y, nv.z, nv.w};
        float vals[2][4];
        #pragma unroll
        for (int n = 0; n < 2; n++) {
            int cg = nbase + wn + n * 16 + l15;
            float btc = bt[cg];
            #pragma unroll
            for (int i = 0; i < 4; i++) {
                float gate = 1.f / (1.f + expf(-(accG[m][n][i] + btc)));
                float fh = accFH[m][n][i] * nvv[i];
                float het = mvv[i] * accH[m][n][i];
                float o = gate * fh + (1.f - gate) * het;
                o = (o > 0.f) ? o : expm1f(o);
                vals[n][i] = o * mvv[i];
            }
        }
        if (LAYER == 0) {
            ushort* Ls = (ushort*)smem;
            int bbase = wid * 512;
            #pragma unroll
            for (int n = 0; n < 2; n++)
                #pragma unroll
                for (int i = 0; i < 4; i++)
                    Ls[bbase + (r4 + i) * 32 + n * 16 + l15] = f2b(vals[n][i]);
            __builtin_amdgcn_s_waitcnt(0);
            #pragma unroll
            for (int it = 0; it < 2; ++it) {
                int lr = (lane >> 3) + it * 8;
                int lc4 = (lane & 7) * 4;
                ushort4 tv = *(const ushort4*)(Ls + bbase + lr * 32 + lc4);
                int rg = rowbase + wm + m * 16 + lr;
                *(ushort4*)(outb + (size_t)rg * 256 + nbase + wn + lc4) = tv;
            }
        } else {
            float* Ls = (float*)smem;
            int bbase = wid * 512;
            #pragma unroll
            for (int n = 0; n < 2; n++)
                #pragma unroll
                for (int i = 0; i < 4; i++)
                    Ls[bbase + (r4 + i) * 32 + n * 16 + l15] = vals[n][i];
            __builtin_amdgcn_s_waitcnt(0);
            #pragma unroll
            for (int it = 0; it < 2; ++it) {
                int lr = (lane >> 3) + it * 8;
                int lc4 = (lane & 7) * 4;
                float4 tv = *(const float4*)(Ls + bbase + lr * 32 + lc4);
                int rg = rowbase + wm + m * 16 + lr;
                int dst = flatscat[rg];
                *(float4*)(outf + (size_t)dst * 256 + nbase + wn + lc4) = tv;
            }
        }
    }
}

extern "C" void kernel_launch(void* const* d_in, const int* in_sizes, int n_in,
                              void* d_out, int out_size, void* d_ws, size_t ws_size,
                              hipStream_t stream) {
    const float* x    = (const float*)d_in[0];
    const void*  msk  = d_in[1];
    const float* ln_g = (const float*)d_in[2];
    const float* ln_b = (const float*)d_in[3];
    const float* w1   = (const float*)d_in[4];
    const float* b1   = (const float*)d_in[5];
    const float* w2   = (const float*)d_in[6];
    const float* b2   = (const float*)d_in[7];
    const float* rot  = (const float*)d_in[8];
    const float* th0  = (const float*)d_in[9];
    const float* wh0  = (const float*)d_in[10];
    const float* wt0  = (const float*)d_in[11];
    const float* bt0  = (const float*)d_in[12];
    const float* th1  = (const float*)d_in[13];
    const float* wh1  = (const float*)d_in[14];
    const float* wt1  = (const float*)d_in[15];
    const float* bt1  = (const float*)d_in[16];

    char* ws = (char*)d_ws;
    ushort* out0 = (ushort*)(ws + OFF_OUT0);
    ushort* dmb  = (ushort*)(ws + OFF_DMB);
    ushort* wb   = (ushort*)(ws + OFF_WB);
    ushort* wbth0 = wb + 0 * 65536;
    ushort* wbwh0 = wb + 1 * 65536;
    ushort* wbwt0 = wb + 2 * 65536;
    ushort* wbth1 = wb + 3 * 65536;
    ushort* wbwh1 = wb + 4 * 65536;
    ushort* wbwt1 = wb + 5 * 65536;
    float* norm = (float*)(ws + OFF_NORM);
    float* mf   = (float*)(ws + OFF_MF);
    int*   bin  = (int*)(ws + OFF_BIN);
    int*   flat = (int*)(ws + OFF_FLAT);
    int*   mski = (int*)(ws + OFF_MSKI);
    int*   hist = (int*)(ws + OFF_HIST);
    int*   offs = (int*)(ws + OFF_OFFS);
    int*   flag = (int*)(ws + OFF_FLAG);
    int*   fixcnt = (int*)(ws + OFF_CNT);
    int*   fixlist = (int*)(ws + OFF_LIST);
    ushort* w1h = (ushort*)(ws + OFF_W1H);
    ushort* w1l = (ushort*)(ws + OFF_W1L);
    ushort* w2h = (ushort*)(ws + OFF_W2H);
    ushort* w2l = (ushort*)(ws + OFF_W2L);
    ushort* rth = (ushort*)(ws + OFF_RH);
    ushort* rtl = (ushort*)(ws + OFF_RL);
    ushort* xdh = (ushort*)d_out;
    ushort* xdl = xdh + (size_t)PTS * DDIM;
    ushort* xnb = (ushort*)((char*)d_out + (size_t)PTS * DDIM * 4);

    hipMemsetAsync(hist, 0, HISTBYTES, stream);
    hipMemsetAsync(fixcnt, 0, 4, stream);
    k_maskflag<<<1, 256, 0, stream>>>((const int*)msk, flag);
    k_masknorm<<<PTS / 256, 256, 0, stream>>>(msk, flag, mski);
    k_wprep<<<dim3(16, 6), 256, 0, stream>>>(th0, wh0, wt0, th1, wh1, wt1,
                                             wbth0, wbwh0, wbwt0, wbth1, wbwh1, wbwt1);
    k_wsplit<<<8, 256, 0, stream>>>(w1, 256, 128, 128, 128, w1h, w1l);
    k_wsplit<<<4, 256, 0, stream>>>(w2, 128, 128, 128, 128, w2h, w2l);
    k_wsplit<<<2, 256, 0, stream>>>(rot, 128, 64, 100, 50, rth, rtl);
    k_stage1<<<PTS / 32, 512, 0, stream>>>(x, ln_g, ln_b, b1, b2,
                                           w1h, w1l, w2h, w2l, rth, rtl, mski,
                                           xnb, xdh, xdl, bin, fixlist, fixcnt);
    k_fixup<<<4096, 64, 0, stream>>>(x, ln_g, ln_b, w1, b1, w2, b2, rot, mski,
                                     fixlist, fixcnt, bin);
    k_count<<<800, 128, 0, stream>>>(bin, hist);
    k_offsets<<<8, 256, 0, stream>>>(hist, offs);
    k_scatter<<<800, 128, 0, stream>>>(bin, offs, mski, flat, mf);
    k_dm<<<800, 512, 0, stream>>>(xdh, xdl, flat, mf, dmb, norm);
    // layer 0 (fused, XCD-locality remapped 1-D grid)
    k_layer<0><<<3200, 512, 0, stream>>>(xnb, flat, wbth0, wbwh0, wbwt0, bt0,
                                         dmb, norm, mf, out0, nullptr, nullptr);
    // layer 1 (fused, scattered fp32 output)
    k_layer<1><<<3200, 512, 0, stream>>>(out0, nullptr, wbth1, wbwh1, wbwt1, bt1,
                                         dmb, norm, mf, nullptr, (float*)d_out, flat);
}

// Round 13
// 492.182 us; speedup vs baseline: 1.0096x; 1.0096x over previous
//
#include <hip/hip_runtime.h>
#include <math.h>

#define BB 8
#define NN 12800
#define FF 256
#define DDIM 128
#define NBINS 100
#define BSIZE 128
#define NROT 50
#define NIDS 199
#define PTS (BB*NN)            // 102400

// ---- workspace layout (bytes) ----
#define OFF_OUT0 ((size_t)157286400)    // 52428800  : out0 bf16 [102400][256]
#define OFF_DMB  ((size_t)209715200)    // 26214400  : dm bf16 [800][128][128]
#define OFF_WB   ((size_t)235929600)    // 786432    : 6 weights bf16 transposed [256][256]
#define OFF_NORM ((size_t)236716032)    // 409600
#define OFF_MF   ((size_t)237125632)    // 409600
#define OFF_BIN  ((size_t)237535232)    // 409600 (int)
#define OFF_FLAT ((size_t)237944832)    // 409600 (int)
#define OFF_MSKI ((size_t)238354432)    // 409600 (int)
#define OFF_HIST ((size_t)238764032)    // 636800 (int)
#define OFF_OFFS ((size_t)239400832)    // 636800 (int)
#define OFF_FLAG ((size_t)240037632)    // 64
#define OFF_CNT  ((size_t)240037696)    // 64
#define OFF_LIST ((size_t)240037760)    // 409600 (int)
#define OFF_W1H  ((size_t)240447360)    // 65536 : w1^T hi bf16 [128][256]
#define OFF_W1L  ((size_t)240512896)    // 65536
#define OFF_W2H  ((size_t)240578432)    // 32768 : w2^T hi bf16 [128][128]
#define OFF_W2L  ((size_t)240611200)    // 32768
#define OFF_RH   ((size_t)240643968)    // 16384 : rot^T hi bf16 [64][128]
#define OFF_RL   ((size_t)240660352)    // 16384
#define HISTBYTES (8*100*199*4)

using short8  = __attribute__((ext_vector_type(8))) short;
using floatx4 = __attribute__((ext_vector_type(4))) float;

__device__ __forceinline__ ushort f2b(float f) {
    unsigned u = __float_as_uint(f);
    unsigned r = (u + 0x7FFFu + ((u >> 16) & 1u)) >> 16;
    return (ushort)r;
}
__device__ __forceinline__ float b2f(ushort h) {
    return __uint_as_float(((unsigned)h) << 16);
}
__device__ __forceinline__ uint4 pack8(const ushort* o) {
    uint4 u;
    u.x = (unsigned)o[0] | ((unsigned)o[1] << 16);
    u.y = (unsigned)o[2] | ((unsigned)o[3] << 16);
    u.z = (unsigned)o[4] | ((unsigned)o[5] << 16);
    u.w = (unsigned)o[6] | ((unsigned)o[7] << 16);
    return u;
}

// ---------- mask dtype sniffing ----------
__global__ void k_maskflag(const int* mi, int* flag) {
    __shared__ int notInt, notFloat;
    if (threadIdx.x == 0) { notInt = 0; notFloat = 0; }
    __syncthreads();
    int v = mi[threadIdx.x];
    if (v != 0 && v != 1) atomicOr(&notInt, 1);
    if (v != 0 && v != 0x3F800000) atomicOr(&notFloat, 1);
    __syncthreads();
    if (threadIdx.x == 0) flag[0] = (!notInt) ? 0 : ((!notFloat) ? 2 : 1);
}

__global__ void k_masknorm(const void* msk, const int* flag, int* mski) {
    int i = blockIdx.x * blockDim.x + threadIdx.x;
    if (i >= PTS) return;
    int f = flag[0];
    int v;
    if (f == 0)      v = ((const int*)msk)[i] != 0;
    else if (f == 2) v = ((const float*)msk)[i] != 0.0f;
    else             v = ((const unsigned char*)msk)[i] != 0;
    mski[i] = v;
}

// ---------- weight prep: fp32 [k][n] -> bf16 transposed [n][k] (GHConv weights) ----------
__global__ __launch_bounds__(256) void k_wprep(
    const float* s0, const float* s1, const float* s2,
    const float* s3, const float* s4, const float* s5,
    ushort* d0, ushort* d1, ushort* d2, ushort* d3, ushort* d4, ushort* d5)
{
    __shared__ float Ls[64 * 65];
    const float* src; ushort* dst;
    switch (blockIdx.y) {
        case 0: src = s0; dst = d0; break;
        case 1: src = s1; dst = d1; break;
        case 2: src = s2; dst = d2; break;
        case 3: src = s3; dst = d3; break;
        case 4: src = s4; dst = d4; break;
        default: src = s5; dst = d5; break;
    }
    int t = blockIdx.x;
    int kb = (t & 3) * 64, nb = (t >> 2) * 64;
    int tid = threadIdx.x;
    for (int q = 0; q < 4; ++q) {
        int g = q * 256 + tid;
        int kl = g >> 4, f4 = g & 15;
        float4 v = *(const float4*)(src + (size_t)(kb + kl) * 256 + nb + f4 * 4);
        Ls[kl * 65 + f4 * 4 + 0] = v.x;
        Ls[kl * 65 + f4 * 4 + 1] = v.y;
        Ls[kl * 65 + f4 * 4 + 2] = v.z;
        Ls[kl * 65 + f4 * 4 + 3] = v.w;
    }
    __syncthreads();
    for (int q = 0; q < 2; ++q) {
        int g = q * 256 + tid;
        int nl = g >> 3, wg = g & 7;
        ushort o[8];
        #pragma unroll
        for (int c = 0; c < 8; ++c) o[c] = f2b(Ls[(wg * 8 + c) * 65 + nl]);
        *(uint4*)(dst + (size_t)(nb + nl) * 256 + kb + wg * 8) = pack8(o);
    }
}

// ---------- split-weight prep: fp32 [K][srcN] -> hi/lo bf16 transposed [N][K] ----------
__global__ __launch_bounds__(256) void k_wsplit(const float* __restrict__ src, int K, int N,
                                               int srcN, int nvalid,
                                               ushort* __restrict__ dh, ushort* __restrict__ dl) {
    __shared__ float Ls[64 * 65];
    int tilesN = N >> 6;
    int kb = (blockIdx.x / tilesN) * 64, nb = (blockIdx.x % tilesN) * 64;
    int tid = threadIdx.x;
    for (int q = 0; q < 4; ++q) {
        int g = q * 256 + tid;
        int kl = g >> 4, c4 = (g & 15) * 4;
        #pragma unroll
        for (int j = 0; j < 4; ++j) {
            int n = nb + c4 + j;
            float v = (n < nvalid) ? src[(size_t)(kb + kl) * srcN + n] : 0.f;
            Ls[kl * 65 + c4 + j] = v;
        }
    }
    __syncthreads();
    for (int q = 0; q < 2; ++q) {
        int g = q * 256 + tid;
        int nl = g >> 3, wg = g & 7;
        ushort oh[8], ol[8];
        #pragma unroll
        for (int c = 0; c < 8; ++c) {
            float v = Ls[(wg * 8 + c) * 65 + nl];
            ushort h = f2b(v);
            oh[c] = h;
            ol[c] = f2b(v - b2f(h));
        }
        *(uint4*)(dh + (size_t)(nb + nl) * K + kb + wg * 8) = pack8(oh);
        *(uint4*)(dl + (size_t)(nb + nl) * K + kb + wg * 8) = pack8(ol);
    }
}

// ---------- MFMA LDS helpers (layout verified in rounds 2-12) ----------
// async staging: linear LDS dest (wave-uniform base + lane*16) with the XOR
// swizzle folded into the per-lane GLOBAL source chunk (involution: dst = src^(row&7)).
__device__ __forceinline__ void stage_async(const ushort* __restrict__ src, size_t pitch,
                                            const int* __restrict__ rowmap, int rowbase, size_t kbase,
                                            ushort* lds, int nrows, int tid) {
    int lane = tid & 63, wid = tid >> 6;
    int total = nrows * 8;
    for (int b0 = 0; b0 < total; b0 += 512) {
        int g = b0 + wid * 64 + lane;
        int row = g >> 3;
        int ck = (g & 7) ^ (row & 7);
        size_t srow = rowmap ? (size_t)rowmap[rowbase + row] : (size_t)(rowbase + row);
        const ushort* gp = src + srow * pitch + kbase + ck * 8;
        ushort* lp = lds + (size_t)(b0 + wid * 64) * 8;   // wave-uniform
        __builtin_amdgcn_global_load_lds(
            (const __attribute__((address_space(1))) unsigned int*)gp,
            (__attribute__((address_space(3))) unsigned int*)lp, 16, 0, 0);
    }
}

__device__ __forceinline__ short8 frag_ld(const ushort* lds, int row, int kc, int lane) {
    int w0 = (kc * 16 + ((lane >> 4) << 2)) ^ ((row & 7) << 2);
    return *(const short8*)((const char*)lds + row * 128 + w0 * 4);
}

// direct global B-fragment load (weights are L2-resident, no swizzle needed)
__device__ __forceinline__ short8 bfrag_g(const ushort* __restrict__ W, int Kpitch,
                                          int row, int k0) {
    return *(const short8*)(W + (size_t)row * Kpitch + k0);
}

// ---------- stage 1 v5b: fused LN + FFN + rot; weights streamed from L2 into VGPRs ----------
// 32 points/block, 512 threads, 32KB LDS, <=128 VGPR -> 2 blocks/CU, ~7 barriers total.
__global__ __launch_bounds__(512, 4) void k_stage1(
    const float* __restrict__ x, const float* __restrict__ g, const float* __restrict__ be,
    const float* __restrict__ b1, const float* __restrict__ b2,
    const ushort* __restrict__ w1h, const ushort* __restrict__ w1l,
    const ushort* __restrict__ w2h, const ushort* __restrict__ w2l,
    const ushort* __restrict__ rth, const ushort* __restrict__ rtl,
    const int* __restrict__ mski,
    ushort* __restrict__ xn_out, ushort* __restrict__ xdh_out, ushort* __restrict__ xdl_out,
    int* __restrict__ bin_out, int* __restrict__ fixlist, int* __restrict__ fixcnt)
{
    __shared__ ushort lXh[4 * 2048];   // 16KB : 4 k-slabs x [32 rows][64 k]
    __shared__ ushort lXl[4 * 2048];   // 16KB
    int tid = threadIdx.x, lane = tid & 63, wid = tid >> 6;
    int base = blockIdx.x * 32;
    int l15 = lane & 15;
    int r4 = (lane >> 4) * 4;
    int kf = (lane >> 4) * 8;          // per-lane k offset within a 32-k fragment

    {   // ---- phase 0: LN (16 threads/point, 16 features each) ----
        int row = tid >> 4, sub = tid & 15;
        const float* xr = x + (size_t)(base + row) * FF + sub * 16;
        float v[16];
        float s = 0.f;
        #pragma unroll
        for (int q = 0; q < 4; ++q) {
            float4 f = *(const float4*)(xr + q * 4);
            v[q*4+0] = f.x; v[q*4+1] = f.y; v[q*4+2] = f.z; v[q*4+3] = f.w;
            s += f.x + f.y + f.z + f.w;
        }
        s += __shfl_xor(s, 1, 16); s += __shfl_xor(s, 2, 16);
        s += __shfl_xor(s, 4, 16); s += __shfl_xor(s, 8, 16);
        float mu = s * (1.f / 256.f);
        float s2 = 0.f;
        #pragma unroll
        for (int q = 0; q < 16; ++q) { float d = v[q] - mu; s2 += d * d; }
        s2 += __shfl_xor(s2, 1, 16); s2 += __shfl_xor(s2, 2, 16);
        s2 += __shfl_xor(s2, 4, 16); s2 += __shfl_xor(s2, 8, 16);
        float rs = 1.0f / sqrtf(s2 * (1.f / 256.f) + 1e-6f);
        ushort* xo = xn_out + (size_t)(base + row) * FF + sub * 16;
        #pragma unroll
        for (int j = 0; j < 2; ++j) {
            int i0 = sub * 16 + j * 8;
            float4 g0 = *(const float4*)(g + i0);
            float4 g1 = *(const float4*)(g + i0 + 4);
            float4 e0 = *(const float4*)(be + i0);
            float4 e1 = *(const float4*)(be + i0 + 4);
            float gv[8] = {g0.x,g0.y,g0.z,g0.w,g1.x,g1.y,g1.z,g1.w};
            float ev[8] = {e0.x,e0.y,e0.z,e0.w,e1.x,e1.y,e1.z,e1.w};
            ushort hh[8], ll[8];
            #pragma unroll
            for (int c = 0; c < 8; ++c) {
                float xv = (v[j*8+c] - mu) * rs * gv[c] + ev[c];
                ushort h = f2b(xv);
                hh[c] = h;
                ll[c] = f2b(xv - b2f(h));
            }
            uint4 uh = pack8(hh), ul = pack8(ll);
            *(uint4*)(xo + j * 8) = uh;
            int kb = i0 >> 6;
            int wg = (i0 & 63) >> 3;
            int w0 = (wg * 4) ^ ((row & 7) << 2);
            *(uint4*)((char*)lXh + kb * 4096 + row * 128 + w0 * 4) = uh;
            *(uint4*)((char*)lXl + kb * 4096 + row * 128 + w0 * 4) = ul;
        }
    }
    __syncthreads();   // xn visible

    int mg = wid >> 2, ng = wid & 3;
    int wm = mg * 16, wn = ng * 32;
    floatx4 zf = {0.f, 0.f, 0.f, 0.f};

    // ---- GEMM1: h = elu(xn @ w1 + b1), M=32 N=128 K=256, B streamed from L2 ----
    floatx4 acc[2];
    acc[0] = zf; acc[1] = zf;
    for (int kb = 0; kb < 4; ++kb) {
        #pragma unroll
        for (int kc = 0; kc < 2; ++kc) {
            int k0 = kb * 64 + kc * 32 + kf;
            short8 ah = frag_ld(lXh + kb * 2048, wm + l15, kc, lane);
            short8 al = frag_ld(lXl + kb * 2048, wm + l15, kc, lane);
            #pragma unroll
            for (int n = 0; n < 2; n++) {
                int rowb = wn + n * 16 + l15;
                short8 bh = bfrag_g(w1h, 256, rowb, k0);
                short8 bl = bfrag_g(w1l, 256, rowb, k0);
                acc[n] = __builtin_amdgcn_mfma_f32_16x16x32_bf16(ah, bh, acc[n], 0, 0, 0);
                acc[n] = __builtin_amdgcn_mfma_f32_16x16x32_bf16(ah, bl, acc[n], 0, 0, 0);
                acc[n] = __builtin_amdgcn_mfma_f32_16x16x32_bf16(al, bh, acc[n], 0, 0, 0);
            }
        }
    }
    __syncthreads();   // GEMM1 reads of lX done
    {   // ep1: h -> lX slabs 0-1
        #pragma unroll
        for (int n = 0; n < 2; n++) {
            int cg = wn + n * 16 + l15;
            float b1v = b1[cg];
            int slab = cg >> 6, c64 = cg & 63;
            int wg = c64 >> 3, e = c64 & 7;
            #pragma unroll
            for (int i = 0; i < 4; i++) {
                int r = wm + r4 + i;
                float hv = acc[n][i] + b1v;
                hv = (hv > 0.f) ? hv : expm1f(hv);
                ushort h = f2b(hv);
                int w0 = (wg * 4) ^ ((r & 7) << 2);
                int idx = slab * 2048 + r * 64 + w0 * 2 + e;
                lXh[idx] = h;
                lXl[idx] = f2b(hv - b2f(h));
            }
        }
    }
    __syncthreads();   // h visible

    // ---- GEMM2: xd = h @ w2 + b2, M=32 N=128 K=128 ----
    floatx4 acc2[2];
    acc2[0] = zf; acc2[1] = zf;
    for (int kb = 0; kb < 2; ++kb) {
        #pragma unroll
        for (int kc = 0; kc < 2; ++kc) {
            int k0 = kb * 64 + kc * 32 + kf;
            short8 ah = frag_ld(lXh + kb * 2048, wm + l15, kc, lane);
            short8 al = frag_ld(lXl + kb * 2048, wm + l15, kc, lane);
            #pragma unroll
            for (int n = 0; n < 2; n++) {
                int rowb = wn + n * 16 + l15;
                short8 bh = bfrag_g(w2h, 128, rowb, k0);
                short8 bl = bfrag_g(w2l, 128, rowb, k0);
                acc2[n] = __builtin_amdgcn_mfma_f32_16x16x32_bf16(ah, bh, acc2[n], 0, 0, 0);
                acc2[n] = __builtin_amdgcn_mfma_f32_16x16x32_bf16(ah, bl, acc2[n], 0, 0, 0);
                acc2[n] = __builtin_amdgcn_mfma_f32_16x16x32_bf16(al, bh, acc2[n], 0, 0, 0);
            }
        }
    }
    __syncthreads();   // GEMM2 reads done (slabs 2-3 free)
    {   // ep2: xd -> global hi/lo + lX slabs 2-3
        #pragma unroll
        for (int n = 0; n < 2; n++) {
            int cg = wn + n * 16 + l15;
            float b2v = b2[cg];
            int slab = 2 + (cg >> 6), c64 = cg & 63;
            int wg = c64 >> 3, e = c64 & 7;
            #pragma unroll
            for (int i = 0; i < 4; i++) {
                int r = wm + r4 + i;
                float xv = acc2[n][i] + b2v;
                ushort h = f2b(xv);
                ushort lo = f2b(xv - b2f(h));
                size_t go = (size_t)(base + r) * DDIM + cg;
                xdh_out[go] = h;
                xdl_out[go] = lo;
                int w0 = (wg * 4) ^ ((r & 7) << 2);
                int idx = slab * 2048 + r * 64 + w0 * 2 + e;
                lXh[idx] = h;
                lXl[idx] = lo;
            }
        }
    }
    __syncthreads();   // xd visible

    // ---- GEMM3: mul = xd @ rot, M=32 N=64 K=128 ----
    floatx4 acc3 = zf;
    int wn3 = ng * 16;
    for (int kb = 0; kb < 2; ++kb) {
        #pragma unroll
        for (int kc = 0; kc < 2; ++kc) {
            int k0 = kb * 64 + kc * 32 + kf;
            short8 ah = frag_ld(lXh + (2 + kb) * 2048, wm + l15, kc, lane);
            short8 al = frag_ld(lXl + (2 + kb) * 2048, wm + l15, kc, lane);
            int rowb = wn3 + l15;
            short8 bh = bfrag_g(rth, 128, rowb, k0);
            short8 bl = bfrag_g(rtl, 128, rowb, k0);
            acc3 = __builtin_amdgcn_mfma_f32_16x16x32_bf16(ah, bh, acc3, 0, 0, 0);
            acc3 = __builtin_amdgcn_mfma_f32_16x16x32_bf16(ah, bl, acc3, 0, 0, 0);
            acc3 = __builtin_amdgcn_mfma_f32_16x16x32_bf16(al, bh, acc3, 0, 0, 0);
        }
    }
    __syncthreads();   // GEMM3 + GEMM2 reads of slabs 0-1 done -> lMul overwrite safe
    float* lMul = (float*)lXh;
    {
        #pragma unroll
        for (int i = 0; i < 4; i++) {
            int r = wm + r4 + i;
            lMul[r * 65 + wn3 + l15] = acc3[i];
        }
    }
    __syncthreads();

    {   // ---- top-2 argmax over [mul, -mul], margin flag (16 thr/pt) ----
        int p = tid >> 4, q = tid & 15;
        float v1 = -1e30f, v2 = -1e30f; int i1 = 1 << 29;
        #pragma unroll
        for (int j = 0; j < 4; ++j) {
            int c = q * 4 + j;
            if (c < 50) {
                float m = lMul[p * 65 + c];
                float wv, lv; int wi, li;
                if (m >= 0.f) { wv = m; wi = c; lv = -m; li = 50 + c; }
                else          { wv = -m; wi = 50 + c; lv = m; li = c; }
                if (wv > v1 || (wv == v1 && wi < i1)) { v2 = v1; v1 = wv; i1 = wi; }
                else if (wv > v2) v2 = wv;
                if (lv > v1 || (lv == v1 && li < i1)) { v2 = v1; v1 = lv; i1 = li; }
                else if (lv > v2) v2 = lv;
            }
        }
        #pragma unroll
        for (int off = 1; off < 16; off <<= 1) {
            float o1 = __shfl_xor(v1, off, 16);
            int   oi = __shfl_xor(i1, off, 16);
            float o2 = __shfl_xor(v2, off, 16);
            bool take = (o1 > v1) || (o1 == v1 && oi < i1);
            float small = take ? v1 : o1;
            if (take) { v1 = o1; i1 = oi; }
            v2 = fmaxf(fmaxf(v2, o2), small);
        }
        if (q == 0) {
            int pt = base + p;
            bin_out[pt] = i1 + (mski[pt] ? 0 : (NBINS - 1));
            float tau = 3e-4f + 1.5e-3f * v1;
            if (v1 - v2 < tau) {
                int pos = atomicAdd(fixcnt, 1);
                fixlist[pos] = pt;
            }
        }
    }
}

// ---------- fp64 fixup for margin-flagged points ----------
__global__ __launch_bounds__(64) void k_fixup(
    const float* __restrict__ x, const float* __restrict__ g, const float* __restrict__ be,
    const float* __restrict__ w1, const float* __restrict__ b1,
    const float* __restrict__ w2, const float* __restrict__ b2,
    const float* __restrict__ rot, const int* __restrict__ mski,
    const int* __restrict__ fixlist, const int* __restrict__ fixcnt,
    int* __restrict__ bin_out)
{
    __shared__ double xn_s[256];
    __shared__ double h_s[128];
    __shared__ double xd_s[128];
    int lane = threadIdx.x;
    int n = fixcnt[0];
    for (int e = blockIdx.x; e < n; e += gridDim.x) {
        int pt = fixlist[e];
        const float* xr = x + (size_t)pt * FF;
        double s = 0.0, xv[4];
        #pragma unroll
        for (int q = 0; q < 4; q++) { xv[q] = (double)xr[lane + q * 64]; s += xv[q]; }
        #pragma unroll
        for (int off = 1; off < 64; off <<= 1) s += __shfl_xor(s, off, 64);
        double mu = s * (1.0 / 256.0);
        double s2 = 0.0;
        #pragma unroll
        for (int q = 0; q < 4; q++) { double d = xv[q] - mu; s2 += d * d; }
        #pragma unroll
        for (int off = 1; off < 64; off <<= 1) s2 += __shfl_xor(s2, off, 64);
        double rs = 1.0 / sqrt(s2 * (1.0 / 256.0) + 1e-6);
        #pragma unroll
        for (int q = 0; q < 4; q++) {
            int i = lane + q * 64;
            xn_s[i] = (xv[q] - mu) * rs * (double)g[i] + (double)be[i];
        }
        __syncthreads();
        #pragma unroll
        for (int q = 0; q < 2; q++) {
            int j = lane + q * 64;
            double a0 = 0.0, a1 = 0.0;
            for (int k = 0; k < FF; k += 2) {
                a0 += xn_s[k] * (double)w1[k * DDIM + j];
                a1 += xn_s[k + 1] * (double)w1[(k + 1) * DDIM + j];
            }
            double a = (double)b1[j] + a0 + a1;
            h_s[j] = (a > 0.0) ? a : expm1(a);
        }
        __syncthreads();
        #pragma unroll
        for (int q = 0; q < 2; q++) {
            int j = lane + q * 64;
            double a0 = 0.0, a1 = 0.0;
            for (int k = 0; k < DDIM; k += 2) {
                a0 += h_s[k] * (double)w2[k * DDIM + j];
                a1 += h_s[k + 1] * (double)w2[(k + 1) * DDIM + j];
            }
            xd_s[j] = (double)b2[j] + a0 + a1;
        }
        __syncthreads();
        double v; int idx;
        if (lane < NROT) {
            double m = 0.0;
            for (int k = 0; k < DDIM; k++) m += xd_s[k] * (double)rot[k * 100 + lane];
            if (m >= 0.0) { v = m; idx = lane; } else { v = -m; idx = 50 + lane; }
        } else { v = -1e300; idx = 1 << 29; }
        #pragma unroll
        for (int off = 1; off < 64; off <<= 1) {
            double ov = __shfl_xor(v, off, 64);
            int oi = __shfl_xor(idx, off, 64);
            if (ov > v || (ov == v && oi < idx)) { v = ov; idx = oi; }
        }
        if (lane == 0) bin_out[pt] = idx + (mski[pt] ? 0 : (NBINS - 1));
        __syncthreads();
    }
}

// ---------- binning: stable counting sort ----------
__global__ void k_count(const int* __restrict__ bin, int* __restrict__ hist) {
    int c = blockIdx.x % 100, b = blockIdx.x / 100;
    int t = threadIdx.x;
    int v = bin[b * NN + c * BSIZE + t];
    atomicAdd(&hist[(b * 100 + c) * NIDS + v], 1);
}

__global__ void k_offsets(const int* __restrict__ hist, int* __restrict__ offs) {
    __shared__ int tot[NIDS];
    __shared__ int start[NIDS];
    int b = blockIdx.x, v = threadIdx.x;
    if (v < NIDS) {
        int s = 0;
        for (int c = 0; c < 100; c++) s += hist[(b * 100 + c) * NIDS + v];
        tot[v] = s;
    }
    __syncthreads();
    if (threadIdx.x == 0) {
        int run = 0;
        for (int i = 0; i < NIDS; i++) { start[i] = run; run += tot[i]; }
    }
    __syncthreads();
    if (v < NIDS) {
        int run = start[v];
        for (int c = 0; c < 100; c++) {
            offs[(b * 100 + c) * NIDS + v] = run;
            run += hist[(b * 100 + c) * NIDS + v];
        }
    }
}

__global__ void k_scatter(const int* __restrict__ bin, const int* __restrict__ offs,
                          const int* __restrict__ mski, int* __restrict__ flat,
                          float* __restrict__ mf) {
    __shared__ int sv[BSIZE];
    int c = blockIdx.x % 100, b = blockIdx.x / 100;
    int t = threadIdx.x;
    int n = c * BSIZE + t;
    int v = bin[b * NN + n];
    sv[t] = v;
    __syncthreads();
    int rank = 0;
    for (int u = 0; u < t; u++) rank += (sv[u] == v);
    int r = offs[(b * 100 + c) * NIDS + v] + rank;
    flat[b * NN + r] = b * NN + n;
    mf[b * NN + r] = mski[b * NN + n] ? 1.0f : 0.0f;
}

// ---------- k_dm v2: per-bin Gram matrix via split-bf16 MFMA, async gather staging ----------
__global__ __launch_bounds__(512, 4) void k_dm(const ushort* __restrict__ xdh, const ushort* __restrict__ xdl,
                                               const int* __restrict__ flat, const float* __restrict__ mf,
                                               ushort* __restrict__ dmb, float* __restrict__ norm) {
    __shared__ ushort lX[32768];   // Xh slabs at [0),[8192); Xl at [16384),[24576); bounce aliases [0..17408)
    __shared__ float na[128];
    __shared__ float ml[128];
    __shared__ float ps[512];
    int tid = threadIdx.x, lane = tid & 63, wid = tid >> 6;
    int g = blockIdx.x;
    int rowbase = g * 128;
    int l15 = lane & 15;
    int r4 = (lane >> 4) * 4;
    int mg = wid >> 2, ng = wid & 3;
    int wm = mg * 64, wn = ng * 32;
    floatx4 zf = {0.f, 0.f, 0.f, 0.f};

    stage_async(xdh, 128, flat, rowbase, 0, lX, 128, tid);
    stage_async(xdh, 128, flat, rowbase, 64, lX + 8192, 128, tid);
    stage_async(xdl, 128, flat, rowbase, 0, lX + 16384, 128, tid);
    stage_async(xdl, 128, flat, rowbase, 64, lX + 24576, 128, tid);
    if (tid < 128) ml[tid] = mf[rowbase + tid];
    __syncthreads();

    {   // na pass
        int row = tid >> 2, part = tid & 3;
        float s = 0.f;
        #pragma unroll
        for (int kb = 0; kb < 2; ++kb) {
            const ushort* ph = lX + kb * 8192 + row * 64 + part * 16;
            #pragma unroll
            for (int q = 0; q < 2; ++q) {
                uint4 uh = *(const uint4*)(ph + q * 8);
                uint4 ul = *(const uint4*)(ph + 16384 + q * 8);
                const unsigned* wh_ = (const unsigned*)&uh;
                const unsigned* wl_ = (const unsigned*)&ul;
                #pragma unroll
                for (int w = 0; w < 4; ++w) {
                    float x0 = b2f((ushort)(wh_[w] & 0xFFFFu)) + b2f((ushort)(wl_[w] & 0xFFFFu));
                    float x1 = b2f((ushort)(wh_[w] >> 16)) + b2f((ushort)(wl_[w] >> 16));
                    s = fmaf(x0, x0, s);
                    s = fmaf(x1, x1, s);
                }
            }
        }
        s += __shfl_xor(s, 1, 4);
        s += __shfl_xor(s, 2, 4);
        if (part == 0) na[row] = s;
    }

    floatx4 acc[4][2];
    #pragma unroll
    for (int m = 0; m < 4; m++) { acc[m][0] = zf; acc[m][1] = zf; }
    for (int kb = 0; kb < 2; ++kb) {
        #pragma unroll
        for (int kc = 0; kc < 2; ++kc) {
            short8 ah[4], al[4], bh[2], bl[2];
            #pragma unroll
            for (int m = 0; m < 4; m++) {
                ah[m] = frag_ld(lX + kb * 8192, wm + m * 16 + l15, kc, lane);
                al[m] = frag_ld(lX + 16384 + kb * 8192, wm + m * 16 + l15, kc, lane);
            }
            #pragma unroll
            for (int n = 0; n < 2; n++) {
                bh[n] = frag_ld(lX + kb * 8192, wn + n * 16 + l15, kc, lane);
                bl[n] = frag_ld(lX + 16384 + kb * 8192, wn + n * 16 + l15, kc, lane);
            }
            #pragma unroll
            for (int m = 0; m < 4; m++)
                #pragma unroll
                for (int n = 0; n < 2; n++) {
                    acc[m][n] = __builtin_amdgcn_mfma_f32_16x16x32_bf16(ah[m], bh[n], acc[m][n], 0, 0, 0);
                    acc[m][n] = __builtin_amdgcn_mfma_f32_16x16x32_bf16(ah[m], bl[n], acc[m][n], 0, 0, 0);
                    acc[m][n] = __builtin_amdgcn_mfma_f32_16x16x32_bf16(al[m], bh[n], acc[m][n], 0, 0, 0);
                }
        }
    }
    __syncthreads();

    ushort* Ls = lX;
    for (int m = 0; m < 4; ++m) {
        int r0 = wm + m * 16 + r4;
        float rs[4] = {0.f, 0.f, 0.f, 0.f};
        #pragma unroll
        for (int n = 0; n < 2; ++n) {
            int c = wn + n * 16 + l15;
            float nac = na[c], mlc = ml[c];
            #pragma unroll
            for (int i = 0; i < 4; ++i) {
                int r = r0 + i;
                float D2 = na[r] - 2.f * acc[m][n][i] + nac;
                float dv = expf(-0.1f * sqrtf(fmaxf(D2, 1e-6f)));
                dv *= ml[r] * mlc;
                rs[i] += dv;
                Ls[r * 136 + c] = f2b(dv);
            }
        }
        #pragma unroll
        for (int off = 1; off < 16; off <<= 1) {
            #pragma unroll
            for (int i = 0; i < 4; ++i) rs[i] += __shfl_xor(rs[i], off, 16);
        }
        if (l15 == 0) {
            #pragma unroll
            for (int i = 0; i < 4; ++i) ps[(r0 + i) * 4 + ng] = rs[i];
        }
    }
    __syncthreads();

    #pragma unroll
    for (int it = 0; it < 4; ++it) {
        int gi = it * 512 + tid;
        int row = gi >> 4, ch = gi & 15;
        uint4 v = *(const uint4*)(Ls + row * 136 + ch * 8);
        *(uint4*)(dmb + (size_t)g * 16384 + row * 128 + ch * 8) = v;
    }
    if (tid < 128) {
        float deg = ps[tid * 4 + 0] + ps[tid * 4 + 1] + ps[tid * 4 + 2] + ps[tid * 4 + 3];
        deg = fminf(deg, 1000.0f);
        norm[rowbase + tid] = (1.0f / sqrtf(deg + 1e-6f)) * ml[tid];
    }
}

// ---------- fused per-layer graph conv v2: merged triple GEMM, 80KB LDS, 2 blocks/CU ----------
// 1-D grid 3200 with XCD-locality remap.
template<int LAYER>
__global__ __launch_bounds__(512, 4) void k_layer(
    const ushort* __restrict__ A, const int* __restrict__ rowmap,
    const ushort* __restrict__ ThT, const ushort* __restrict__ WhT, const ushort* __restrict__ WtT,
    const float* __restrict__ bt, const ushort* __restrict__ dmb,
    const float* __restrict__ norm, const float* __restrict__ mf,
    ushort* __restrict__ outb, float* __restrict__ outf, const int* __restrict__ flatscat)
{
    __shared__ char smem[81920];
    ushort* lAbuf = (ushort*)smem;                 // 2 x 16KB A ping
    ushort* lB    = (ushort*)(smem + 32768);       // 6 x 8KB: th0 th1 wh0 wh1 wt0 wt1
    ushort* lT    = (ushort*)smem;                 // post-GEMM: 2 x 8KB T^T j-slabs
    ushort* ldm   = (ushort*)(smem + 32768);       // post-GEMM: 2 x 16KB dm slabs

    int tid = threadIdx.x, lane = tid & 63, wid = tid >> 6;
    int bid = blockIdx.x;
    int grp = bid >> 5, within = bid & 31;
    int nh = within >> 3, g = grp * 8 + (within & 7);
    int rowbase = g * 128, nbase = nh * 64;
    int l15 = lane & 15;
    int r4 = (lane >> 4) * 4;
    int wm = (wid >> 1) * 32, wn = (wid & 1) * 32;
    const ushort* dmg = dmb + (size_t)g * 16384;
    floatx4 zf = {0.f, 0.f, 0.f, 0.f};

    stage_async(A, 256, rowmap, rowbase, 0, lAbuf, 128, tid);
    stage_async(ThT, 256, nullptr, nbase, 0, lB + 0 * 4096, 64, tid);
    stage_async(WhT, 256, nullptr, nbase, 0, lB + 2 * 4096, 64, tid);
    stage_async(WtT, 256, nullptr, nbase, 0, lB + 4 * 4096, 64, tid);
    __syncthreads();

    floatx4 accT[2][2], accH[2][2], accG[2][2];
    #pragma unroll
    for (int m = 0; m < 2; m++)
        #pragma unroll
        for (int n = 0; n < 2; n++) { accT[m][n] = zf; accH[m][n] = zf; accG[m][n] = zf; }
    for (int kb = 0; kb < 4; ++kb) {
        if (kb < 3) {
            int pp = (kb + 1) & 1;
            stage_async(A, 256, rowmap, rowbase, (size_t)(kb + 1) * 64, lAbuf + pp * 8192, 128, tid);
            stage_async(ThT, 256, nullptr, nbase, (size_t)(kb + 1) * 64, lB + (0 + pp) * 4096, 64, tid);
            stage_async(WhT, 256, nullptr, nbase, (size_t)(kb + 1) * 64, lB + (2 + pp) * 4096, 64, tid);
            stage_async(WtT, 256, nullptr, nbase, (size_t)(kb + 1) * 64, lB + (4 + pp) * 4096, 64, tid);
        }
        const ushort* lA = lAbuf + (kb & 1) * 8192;
        const ushort* sTh = lB + (0 + (kb & 1)) * 4096;
        const ushort* sWh = lB + (2 + (kb & 1)) * 4096;
        const ushort* sWt = lB + (4 + (kb & 1)) * 4096;
        #pragma unroll
        for (int kc = 0; kc < 2; ++kc) {
            short8 a[2], bt_[2], bh_[2], bg_[2];
            #pragma unroll
            for (int m = 0; m < 2; m++) a[m] = frag_ld(lA, wm + m * 16 + l15, kc, lane);
            #pragma unroll
            for (int n = 0; n < 2; n++) {
                bt_[n] = frag_ld(sTh, wn + n * 16 + l15, kc, lane);
                bh_[n] = frag_ld(sWh, wn + n * 16 + l15, kc, lane);
                bg_[n] = frag_ld(sWt, wn + n * 16 + l15, kc, lane);
            }
            #pragma unroll
            for (int m = 0; m < 2; m++)
                #pragma unroll
                for (int n = 0; n < 2; n++) {
                    accT[m][n] = __builtin_amdgcn_mfma_f32_16x16x32_bf16(a[m], bt_[n], accT[m][n], 0, 0, 0);
                    accH[m][n] = __builtin_amdgcn_mfma_f32_16x16x32_bf16(a[m], bh_[n], accH[m][n], 0, 0, 0);
                    accG[m][n] = __builtin_amdgcn_mfma_f32_16x16x32_bf16(a[m], bg_[n], accG[m][n], 0, 0, 0);
                }
        }
        __syncthreads();
    }

    stage_async(dmg, 128, nullptr, 0, 0, ldm, 128, tid);
    stage_async(dmg, 128, nullptr, 0, 64, ldm + 8192, 128, tid);

    {   // T^T (scaled by norm, bf16, frag-swizzled) into lT j-slabs
        #pragma unroll
        for (int m = 0; m < 2; m++) {
            float4 nv = *(const float4*)(norm + rowbase + wm + m * 16 + r4);
            float nvv[4] = {nv.x, nv.y, nv.z, nv.w};
            int jloc0 = wm + m * 16 + r4;
            int jb = jloc0 >> 6, jj = jloc0 & 63;
            #pragma unroll
            for (int n = 0; n < 2; n++) {
                int cloc = wn + n * 16 + l15;
                char* bp = (char*)(lT + jb * 4096) + cloc * 128;
                int cx = (cloc & 7) << 2;
                ushort t0 = f2b(accT[m][n][0] * nvv[0]);
                ushort t1 = f2b(accT[m][n][1] * nvv[1]);
                ushort t2 = f2b(accT[m][n][2] * nvv[2]);
                ushort t3 = f2b(accT[m][n][3] * nvv[3]);
                *(unsigned*)(bp + ((((jj >> 1) + 0) ^ cx) << 2)) = (unsigned)t0 | ((unsigned)t1 << 16);
                *(unsigned*)(bp + ((((jj >> 1) + 1) ^ cx) << 2)) = (unsigned)t2 | ((unsigned)t3 << 16);
            }
        }
    }
    __syncthreads();

    floatx4 accFH[2][2];
    #pragma unroll
    for (int m = 0; m < 2; m++) { accFH[m][0] = zf; accFH[m][1] = zf; }
    for (int kb = 0; kb < 2; ++kb) {
        #pragma unroll
        for (int kc = 0; kc < 2; ++kc) {
            short8 a[2], b[2];
            #pragma unroll
            for (int m = 0; m < 2; m++) a[m] = frag_ld(ldm + kb * 8192, wm + m * 16 + l15, kc, lane);
            #pragma unroll
            for (int n = 0; n < 2; n++) b[n] = frag_ld(lT + kb * 4096, wn + n * 16 + l15, kc, lane);
            #pragma unroll
            for (int m = 0; m < 2; m++)
                #pragma unroll
                for (int n = 0; n < 2; n++)
                    accFH[m][n] = __builtin_amdgcn_mfma_f32_16x16x32_bf16(a[m], b[n], accFH[m][n], 0, 0, 0);
        }
    }
    __syncthreads();

    for (int m = 0; m < 2; m++) {
        int r0l = wm + m * 16 + r4;
        int r0g = rowbase + r0l;
        float4 mv = *(const float4*)(mf + r0g);
        float4 nv = *(const float4*)(norm + r0g);
        float mvv[4] = {mv.x, mv.y, mv.z, mv.w};
        float nvv[4] = {nv.x, nv.y, nv.z, nv.w};
        float vals[2][4];
        #pragma unroll
        for (int n = 0; n < 2; n++) {
            int cg = nbase + wn + n * 16 + l15;
            float btc = bt[cg];
            #pragma unroll
            for (int i = 0; i < 4; i++) {
                float gate = 1.f / (1.f + expf(-(accG[m][n][i] + btc)));
                float fh = accFH[m][n][i] * nvv[i];
                float het = mvv[i] * accH[m][n][i];
                float o = gate * fh + (1.f - gate) * het;
                o = (o > 0.f) ? o : expm1f(o);
                vals[n][i] = o * mvv[i];
            }
        }
        if (LAYER == 0) {
            ushort* Ls = (ushort*)smem;
            int bbase = wid * 512;
            #pragma unroll
            for (int n = 0; n < 2; n++)
                #pragma unroll
                for (int i = 0; i < 4; i++)
                    Ls[bbase + (r4 + i) * 32 + n * 16 + l15] = f2b(vals[n][i]);
            __builtin_amdgcn_s_waitcnt(0);
            #pragma unroll
            for (int it = 0; it < 2; ++it) {
                int lr = (lane >> 3) + it * 8;
                int lc4 = (lane & 7) * 4;
                ushort4 tv = *(const ushort4*)(Ls + bbase + lr * 32 + lc4);
                int rg = rowbase + wm + m * 16 + lr;
                *(ushort4*)(outb + (size_t)rg * 256 + nbase + wn + lc4) = tv;
            }
        } else {
            float* Ls = (float*)smem;
            int bbase = wid * 512;
            #pragma unroll
            for (int n = 0; n < 2; n++)
                #pragma unroll
                for (int i = 0; i < 4; i++)
                    Ls[bbase + (r4 + i) * 32 + n * 16 + l15] = vals[n][i];
            __builtin_amdgcn_s_waitcnt(0);
            #pragma unroll
            for (int it = 0; it < 2; ++it) {
                int lr = (lane >> 3) + it * 8;
                int lc4 = (lane & 7) * 4;
                float4 tv = *(const float4*)(Ls + bbase + lr * 32 + lc4);
                int rg = rowbase + wm + m * 16 + lr;
                int dst = flatscat[rg];
                *(float4*)(outf + (size_t)dst * 256 + nbase + wn + lc4) = tv;
            }
        }
    }
}

extern "C" void kernel_launch(void* const* d_in, const int* in_sizes, int n_in,
                              void* d_out, int out_size, void* d_ws, size_t ws_size,
                              hipStream_t stream) {
    const float* x    = (const float*)d_in[0];
    const void*  msk  = d_in[1];
    const float* ln_g = (const float*)d_in[2];
    const float* ln_b = (const float*)d_in[3];
    const float* w1   = (const float*)d_in[4];
    const float* b1   = (const float*)d_in[5];
    const float* w2   = (const float*)d_in[6];
    const float* b2   = (const float*)d_in[7];
    const float* rot  = (const float*)d_in[8];
    const float* th0  = (const float*)d_in[9];
    const float* wh0  = (const float*)d_in[10];
    const float* wt0  = (const float*)d_in[11];
    const float* bt0  = (const float*)d_in[12];
    const float* th1  = (const float*)d_in[13];
    const float* wh1  = (const float*)d_in[14];
    const float* wt1  = (const float*)d_in[15];
    const float* bt1  = (const float*)d_in[16];

    char* ws = (char*)d_ws;
    ushort* out0 = (ushort*)(ws + OFF_OUT0);
    ushort* dmb  = (ushort*)(ws + OFF_DMB);
    ushort* wb   = (ushort*)(ws + OFF_WB);
    ushort* wbth0 = wb + 0 * 65536;
    ushort* wbwh0 = wb + 1 * 65536;
    ushort* wbwt0 = wb + 2 * 65536;
    ushort* wbth1 = wb + 3 * 65536;
    ushort* wbwh1 = wb + 4 * 65536;
    ushort* wbwt1 = wb + 5 * 65536;
    float* norm = (float*)(ws + OFF_NORM);
    float* mf   = (float*)(ws + OFF_MF);
    int*   bin  = (int*)(ws + OFF_BIN);
    int*   flat = (int*)(ws + OFF_FLAT);
    int*   mski = (int*)(ws + OFF_MSKI);
    int*   hist = (int*)(ws + OFF_HIST);
    int*   offs = (int*)(ws + OFF_OFFS);
    int*   flag = (int*)(ws + OFF_FLAG);
    int*   fixcnt = (int*)(ws + OFF_CNT);
    int*   fixlist = (int*)(ws + OFF_LIST);
    ushort* w1h = (ushort*)(ws + OFF_W1H);
    ushort* w1l = (ushort*)(ws + OFF_W1L);
    ushort* w2h = (ushort*)(ws + OFF_W2H);
    ushort* w2l = (ushort*)(ws + OFF_W2L);
    ushort* rth = (ushort*)(ws + OFF_RH);
    ushort* rtl = (ushort*)(ws + OFF_RL);
    ushort* xdh = (ushort*)d_out;
    ushort* xdl = xdh + (size_t)PTS * DDIM;
    ushort* xnb = (ushort*)((char*)d_out + (size_t)PTS * DDIM * 4);

    hipMemsetAsync(hist, 0, HISTBYTES, stream);
    hipMemsetAsync(fixcnt, 0, 4, stream);
    k_maskflag<<<1, 256, 0, stream>>>((const int*)msk, flag);
    k_masknorm<<<PTS / 256, 256, 0, stream>>>(msk, flag, mski);
    k_wprep<<<dim3(16, 6), 256, 0, stream>>>(th0, wh0, wt0, th1, wh1, wt1,
                                             wbth0, wbwh0, wbwt0, wbth1, wbwh1, wbwt1);
    k_wsplit<<<8, 256, 0, stream>>>(w1, 256, 128, 128, 128, w1h, w1l);
    k_wsplit<<<4, 256, 0, stream>>>(w2, 128, 128, 128, 128, w2h, w2l);
    k_wsplit<<<2, 256, 0, stream>>>(rot, 128, 64, 100, 50, rth, rtl);
    k_stage1<<<PTS / 32, 512, 0, stream>>>(x, ln_g, ln_b, b1, b2,
                                           w1h, w1l, w2h, w2l, rth, rtl, mski,
                                           xnb, xdh, xdl, bin, fixlist, fixcnt);
    k_fixup<<<4096, 64, 0, stream>>>(x, ln_g, ln_b, w1, b1, w2, b2, rot, mski,
                                     fixlist, fixcnt, bin);
    k_count<<<800, 128, 0, stream>>>(bin, hist);
    k_offsets<<<8, 256, 0, stream>>>(hist, offs);
    k_scatter<<<800, 128, 0, stream>>>(bin, offs, mski, flat, mf);
    k_dm<<<800, 512, 0, stream>>>(xdh, xdl, flat, mf, dmb, norm);
    // layer 0 (fused, XCD-locality remapped 1-D grid)
    k_layer<0><<<3200, 512, 0, stream>>>(xnb, flat, wbth0, wbwh0, wbwt0, bt0,
                                         dmb, norm, mf, out0, nullptr, nullptr);
    // layer 1 (fused, scattered fp32 output)
    k_layer<1><<<3200, 512, 0, stream>>>(out0, nullptr, wbth1, wbwh1, wbwt1, bt1,
                                         dmb, norm, mf, nullptr, (float*)d_out, flat);
}

// Round 14
// 389.669 us; speedup vs baseline: 1.2752x; 1.2631x over previous
//
#include <hip/hip_runtime.h>
#include <math.h>

#define BB 8
#define NN 12800
#define FF 256
#define DDIM 128
#define NBINS 100
#define BSIZE 128
#define NROT 50
#define NIDS 199
#define PTS (BB*NN)            // 102400

// ---- workspace layout (bytes) ----
#define OFF_OUT0 ((size_t)157286400)    // 52428800  : out0 bf16 [102400][256]
#define OFF_DMB  ((size_t)209715200)    // 26214400  : dm bf16 [800][128][128]
#define OFF_WB   ((size_t)235929600)    // 786432    : 6 weights bf16 transposed [256][256]
#define OFF_NORM ((size_t)236716032)    // 409600
#define OFF_MF   ((size_t)237125632)    // 409600
#define OFF_BIN  ((size_t)237535232)    // 409600 (int)
#define OFF_FLAT ((size_t)237944832)    // 409600 (int)
#define OFF_MSKI ((size_t)238354432)    // 409600 (int)
#define OFF_HIST ((size_t)238764032)    // 636800 (int)
#define OFF_OFFS ((size_t)239400832)    // 636800 (int)
#define OFF_FLAG ((size_t)240037632)    // 64
#define OFF_CNT  ((size_t)240037696)    // 64
#define OFF_LIST ((size_t)240037760)    // 409600 (int)
#define OFF_W1H  ((size_t)240447360)    // 65536 : w1^T hi bf16 [128][256]
#define OFF_W1L  ((size_t)240512896)    // 65536
#define OFF_W2H  ((size_t)240578432)    // 32768 : w2^T hi bf16 [128][128]
#define OFF_W2L  ((size_t)240611200)    // 32768
#define OFF_RH   ((size_t)240643968)    // 16384 : rot^T hi bf16 [64][128]
#define OFF_RL   ((size_t)240660352)    // 16384
#define HISTBYTES (8*100*199*4)

using short8  = __attribute__((ext_vector_type(8))) short;
using floatx4 = __attribute__((ext_vector_type(4))) float;

__device__ __forceinline__ ushort f2b(float f) {
    unsigned u = __float_as_uint(f);
    unsigned r = (u + 0x7FFFu + ((u >> 16) & 1u)) >> 16;
    return (ushort)r;
}
__device__ __forceinline__ float b2f(ushort h) {
    return __uint_as_float(((unsigned)h) << 16);
}
__device__ __forceinline__ uint4 pack8(const ushort* o) {
    uint4 u;
    u.x = (unsigned)o[0] | ((unsigned)o[1] << 16);
    u.y = (unsigned)o[2] | ((unsigned)o[3] << 16);
    u.z = (unsigned)o[4] | ((unsigned)o[5] << 16);
    u.w = (unsigned)o[6] | ((unsigned)o[7] << 16);
    return u;
}

// ---------- mask dtype sniffing ----------
__global__ void k_maskflag(const int* mi, int* flag) {
    __shared__ int notInt, notFloat;
    if (threadIdx.x == 0) { notInt = 0; notFloat = 0; }
    __syncthreads();
    int v = mi[threadIdx.x];
    if (v != 0 && v != 1) atomicOr(&notInt, 1);
    if (v != 0 && v != 0x3F800000) atomicOr(&notFloat, 1);
    __syncthreads();
    if (threadIdx.x == 0) flag[0] = (!notInt) ? 0 : ((!notFloat) ? 2 : 1);
}

__global__ void k_masknorm(const void* msk, const int* flag, int* mski) {
    int i = blockIdx.x * blockDim.x + threadIdx.x;
    if (i >= PTS) return;
    int f = flag[0];
    int v;
    if (f == 0)      v = ((const int*)msk)[i] != 0;
    else if (f == 2) v = ((const float*)msk)[i] != 0.0f;
    else             v = ((const unsigned char*)msk)[i] != 0;
    mski[i] = v;
}

// ---------- weight prep: fp32 [k][n] -> bf16 transposed [n][k] (GHConv weights) ----------
__global__ __launch_bounds__(256) void k_wprep(
    const float* s0, const float* s1, const float* s2,
    const float* s3, const float* s4, const float* s5,
    ushort* d0, ushort* d1, ushort* d2, ushort* d3, ushort* d4, ushort* d5)
{
    __shared__ float Ls[64 * 65];
    const float* src; ushort* dst;
    switch (blockIdx.y) {
        case 0: src = s0; dst = d0; break;
        case 1: src = s1; dst = d1; break;
        case 2: src = s2; dst = d2; break;
        case 3: src = s3; dst = d3; break;
        case 4: src = s4; dst = d4; break;
        default: src = s5; dst = d5; break;
    }
    int t = blockIdx.x;
    int kb = (t & 3) * 64, nb = (t >> 2) * 64;
    int tid = threadIdx.x;
    for (int q = 0; q < 4; ++q) {
        int g = q * 256 + tid;
        int kl = g >> 4, f4 = g & 15;
        float4 v = *(const float4*)(src + (size_t)(kb + kl) * 256 + nb + f4 * 4);
        Ls[kl * 65 + f4 * 4 + 0] = v.x;
        Ls[kl * 65 + f4 * 4 + 1] = v.y;
        Ls[kl * 65 + f4 * 4 + 2] = v.z;
        Ls[kl * 65 + f4 * 4 + 3] = v.w;
    }
    __syncthreads();
    for (int q = 0; q < 2; ++q) {
        int g = q * 256 + tid;
        int nl = g >> 3, wg = g & 7;
        ushort o[8];
        #pragma unroll
        for (int c = 0; c < 8; ++c) o[c] = f2b(Ls[(wg * 8 + c) * 65 + nl]);
        *(uint4*)(dst + (size_t)(nb + nl) * 256 + kb + wg * 8) = pack8(o);
    }
}

// ---------- split-weight prep: fp32 [K][srcN] -> hi/lo bf16 transposed [N][K] ----------
__global__ __launch_bounds__(256) void k_wsplit(const float* __restrict__ src, int K, int N,
                                               int srcN, int nvalid,
                                               ushort* __restrict__ dh, ushort* __restrict__ dl) {
    __shared__ float Ls[64 * 65];
    int tilesN = N >> 6;
    int kb = (blockIdx.x / tilesN) * 64, nb = (blockIdx.x % tilesN) * 64;
    int tid = threadIdx.x;
    for (int q = 0; q < 4; ++q) {
        int g = q * 256 + tid;
        int kl = g >> 4, c4 = (g & 15) * 4;
        #pragma unroll
        for (int j = 0; j < 4; ++j) {
            int n = nb + c4 + j;
            float v = (n < nvalid) ? src[(size_t)(kb + kl) * srcN + n] : 0.f;
            Ls[kl * 65 + c4 + j] = v;
        }
    }
    __syncthreads();
    for (int q = 0; q < 2; ++q) {
        int g = q * 256 + tid;
        int nl = g >> 3, wg = g & 7;
        ushort oh[8], ol[8];
        #pragma unroll
        for (int c = 0; c < 8; ++c) {
            float v = Ls[(wg * 8 + c) * 65 + nl];
            ushort h = f2b(v);
            oh[c] = h;
            ol[c] = f2b(v - b2f(h));
        }
        *(uint4*)(dh + (size_t)(nb + nl) * K + kb + wg * 8) = pack8(oh);
        *(uint4*)(dl + (size_t)(nb + nl) * K + kb + wg * 8) = pack8(ol);
    }
}

// ---------- MFMA LDS helpers (layout verified in rounds 2-11) ----------
// async staging: linear LDS dest (wave-uniform base + lane*16) with the XOR
// swizzle folded into the per-lane GLOBAL source chunk (involution: dst = src^(row&7)).
__device__ __forceinline__ void stage_async(const ushort* __restrict__ src, size_t pitch,
                                            const int* __restrict__ rowmap, int rowbase, size_t kbase,
                                            ushort* lds, int nrows, int tid) {
    int lane = tid & 63, wid = tid >> 6;
    int total = nrows * 8;
    for (int b0 = 0; b0 < total; b0 += 512) {
        int g = b0 + wid * 64 + lane;
        int row = g >> 3;
        int ck = (g & 7) ^ (row & 7);
        size_t srow = rowmap ? (size_t)rowmap[rowbase + row] : (size_t)(rowbase + row);
        const ushort* gp = src + srow * pitch + kbase + ck * 8;
        ushort* lp = lds + (size_t)(b0 + wid * 64) * 8;   // wave-uniform
        __builtin_amdgcn_global_load_lds(
            (const __attribute__((address_space(1))) unsigned int*)gp,
            (__attribute__((address_space(3))) unsigned int*)lp, 16, 0, 0);
    }
}

__device__ __forceinline__ short8 frag_ld(const ushort* lds, int row, int kc, int lane) {
    int w0 = (kc * 16 + ((lane >> 4) << 2)) ^ ((row & 7) << 2);
    return *(const short8*)((const char*)lds + row * 128 + w0 * 4);
}

// ---------- stage 1 v4: fused LN + FFN + rot via split-bf16 MFMA ----------
// 32 points/block, 512 threads, 64KB LDS -> 2 blocks/CU.
__global__ __launch_bounds__(512, 4) void k_stage1(
    const float* __restrict__ x, const float* __restrict__ g, const float* __restrict__ be,
    const float* __restrict__ b1, const float* __restrict__ b2,
    const ushort* __restrict__ w1h, const ushort* __restrict__ w1l,
    const ushort* __restrict__ w2h, const ushort* __restrict__ w2l,
    const ushort* __restrict__ rth, const ushort* __restrict__ rtl,
    const int* __restrict__ mski,
    ushort* __restrict__ xn_out, ushort* __restrict__ xdh_out, ushort* __restrict__ xdl_out,
    int* __restrict__ bin_out, int* __restrict__ fixlist, int* __restrict__ fixcnt)
{
    __shared__ ushort lXh[4 * 2048];   // 16KB : 4 k-slabs x [32 rows][64 k]
    __shared__ ushort lXl[4 * 2048];   // 16KB
    __shared__ ushort lWh[8192];       // 16KB : single weight slab [128][64]
    __shared__ ushort lWl[8192];       // 16KB
    int tid = threadIdx.x, lane = tid & 63, wid = tid >> 6;
    int base = blockIdx.x * 32;
    int l15 = lane & 15;
    int r4 = (lane >> 4) * 4;

    stage_async(w1h, 256, nullptr, 0, 0, lWh, 128, tid);
    stage_async(w1l, 256, nullptr, 0, 0, lWl, 128, tid);

    {   // ---- phase 0: LN (16 threads/point, 16 features each) ----
        int row = tid >> 4, sub = tid & 15;
        const float* xr = x + (size_t)(base + row) * FF + sub * 16;
        float v[16];
        float s = 0.f;
        #pragma unroll
        for (int q = 0; q < 4; ++q) {
            float4 f = *(const float4*)(xr + q * 4);
            v[q*4+0] = f.x; v[q*4+1] = f.y; v[q*4+2] = f.z; v[q*4+3] = f.w;
            s += f.x + f.y + f.z + f.w;
        }
        s += __shfl_xor(s, 1, 16); s += __shfl_xor(s, 2, 16);
        s += __shfl_xor(s, 4, 16); s += __shfl_xor(s, 8, 16);
        float mu = s * (1.f / 256.f);
        float s2 = 0.f;
        #pragma unroll
        for (int q = 0; q < 16; ++q) { float d = v[q] - mu; s2 += d * d; }
        s2 += __shfl_xor(s2, 1, 16); s2 += __shfl_xor(s2, 2, 16);
        s2 += __shfl_xor(s2, 4, 16); s2 += __shfl_xor(s2, 8, 16);
        float rs = 1.0f / sqrtf(s2 * (1.f / 256.f) + 1e-6f);
        ushort* xo = xn_out + (size_t)(base + row) * FF + sub * 16;
        #pragma unroll
        for (int j = 0; j < 2; ++j) {
            int i0 = sub * 16 + j * 8;
            float4 g0 = *(const float4*)(g + i0);
            float4 g1 = *(const float4*)(g + i0 + 4);
            float4 e0 = *(const float4*)(be + i0);
            float4 e1 = *(const float4*)(be + i0 + 4);
            float gv[8] = {g0.x,g0.y,g0.z,g0.w,g1.x,g1.y,g1.z,g1.w};
            float ev[8] = {e0.x,e0.y,e0.z,e0.w,e1.x,e1.y,e1.z,e1.w};
            ushort hh[8], ll[8];
            #pragma unroll
            for (int c = 0; c < 8; ++c) {
                float xv = (v[j*8+c] - mu) * rs * gv[c] + ev[c];
                ushort h = f2b(xv);
                hh[c] = h;
                ll[c] = f2b(xv - b2f(h));
            }
            uint4 uh = pack8(hh), ul = pack8(ll);
            *(uint4*)(xo + j * 8) = uh;
            int kb = i0 >> 6;
            int wg = (i0 & 63) >> 3;
            int w0 = (wg * 4) ^ ((row & 7) << 2);
            *(uint4*)((char*)lXh + kb * 4096 + row * 128 + w0 * 4) = uh;
            *(uint4*)((char*)lXl + kb * 4096 + row * 128 + w0 * 4) = ul;
        }
    }
    __syncthreads();   // xn visible + w1 slab0 ready

    int mg = wid >> 2, ng = wid & 3;
    int wm = mg * 16, wn = ng * 32;
    floatx4 zf = {0.f, 0.f, 0.f, 0.f};

    // ---- GEMM1: h = elu(xn @ w1 + b1), M=32 N=128 K=256 ----
    floatx4 acc[2];
    acc[0] = zf; acc[1] = zf;
    for (int kb = 0; kb < 4; ++kb) {
        #pragma unroll
        for (int kc = 0; kc < 2; ++kc) {
            short8 ah, al, bh[2], bl[2];
            ah = frag_ld(lXh + kb * 2048, wm + l15, kc, lane);
            al = frag_ld(lXl + kb * 2048, wm + l15, kc, lane);
            #pragma unroll
            for (int n = 0; n < 2; n++) {
                bh[n] = frag_ld(lWh, wn + n * 16 + l15, kc, lane);
                bl[n] = frag_ld(lWl, wn + n * 16 + l15, kc, lane);
            }
            #pragma unroll
            for (int n = 0; n < 2; n++) {
                acc[n] = __builtin_amdgcn_mfma_f32_16x16x32_bf16(ah, bh[n], acc[n], 0, 0, 0);
                acc[n] = __builtin_amdgcn_mfma_f32_16x16x32_bf16(ah, bl[n], acc[n], 0, 0, 0);
                acc[n] = __builtin_amdgcn_mfma_f32_16x16x32_bf16(al, bh[n], acc[n], 0, 0, 0);
            }
        }
        __syncthreads();
        if (kb < 3) {
            stage_async(w1h, 256, nullptr, 0, (size_t)(kb + 1) * 64, lWh, 128, tid);
            stage_async(w1l, 256, nullptr, 0, (size_t)(kb + 1) * 64, lWl, 128, tid);
            __syncthreads();
        }
    }
    stage_async(w2h, 128, nullptr, 0, 0, lWh, 128, tid);
    stage_async(w2l, 128, nullptr, 0, 0, lWl, 128, tid);
    {
        #pragma unroll
        for (int n = 0; n < 2; n++) {
            int cg = wn + n * 16 + l15;
            float b1v = b1[cg];
            int slab = cg >> 6, c64 = cg & 63;
            int wg = c64 >> 3, e = c64 & 7;
            #pragma unroll
            for (int i = 0; i < 4; i++) {
                int r = wm + r4 + i;
                float hv = acc[n][i] + b1v;
                hv = (hv > 0.f) ? hv : expm1f(hv);
                ushort h = f2b(hv);
                int w0 = (wg * 4) ^ ((r & 7) << 2);
                int idx = slab * 2048 + r * 64 + w0 * 2 + e;
                lXh[idx] = h;
                lXl[idx] = f2b(hv - b2f(h));
            }
        }
    }
    __syncthreads();   // h visible + w2 slab0 ready

    // ---- GEMM2: xd = h @ w2 + b2, M=32 N=128 K=128 ----
    floatx4 acc2[2];
    acc2[0] = zf; acc2[1] = zf;
    for (int kb = 0; kb < 2; ++kb) {
        #pragma unroll
        for (int kc = 0; kc < 2; ++kc) {
            short8 ah, al, bh[2], bl[2];
            ah = frag_ld(lXh + kb * 2048, wm + l15, kc, lane);
            al = frag_ld(lXl + kb * 2048, wm + l15, kc, lane);
            #pragma unroll
            for (int n = 0; n < 2; n++) {
                bh[n] = frag_ld(lWh, wn + n * 16 + l15, kc, lane);
                bl[n] = frag_ld(lWl, wn + n * 16 + l15, kc, lane);
            }
            #pragma unroll
            for (int n = 0; n < 2; n++) {
                acc2[n] = __builtin_amdgcn_mfma_f32_16x16x32_bf16(ah, bh[n], acc2[n], 0, 0, 0);
                acc2[n] = __builtin_amdgcn_mfma_f32_16x16x32_bf16(ah, bl[n], acc2[n], 0, 0, 0);
                acc2[n] = __builtin_amdgcn_mfma_f32_16x16x32_bf16(al, bh[n], acc2[n], 0, 0, 0);
            }
        }
        __syncthreads();
        if (kb == 0) {
            stage_async(w2h, 128, nullptr, 0, 64, lWh, 128, tid);
            stage_async(w2l, 128, nullptr, 0, 64, lWl, 128, tid);
            __syncthreads();
        }
    }
    stage_async(rth, 128, nullptr, 0, 0, lWh, 64, tid);
    stage_async(rtl, 128, nullptr, 0, 0, lWl, 64, tid);
    stage_async(rth, 128, nullptr, 0, 64, lWh + 4096, 64, tid);
    stage_async(rtl, 128, nullptr, 0, 64, lWl + 4096, 64, tid);
    {
        #pragma unroll
        for (int n = 0; n < 2; n++) {
            int cg = wn + n * 16 + l15;
            float b2v = b2[cg];
            int slab = 2 + (cg >> 6), c64 = cg & 63;
            int wg = c64 >> 3, e = c64 & 7;
            #pragma unroll
            for (int i = 0; i < 4; i++) {
                int r = wm + r4 + i;
                float xv = acc2[n][i] + b2v;
                ushort h = f2b(xv);
                ushort lo = f2b(xv - b2f(h));
                size_t go = (size_t)(base + r) * DDIM + cg;
                xdh_out[go] = h;
                xdl_out[go] = lo;
                int w0 = (wg * 4) ^ ((r & 7) << 2);
                int idx = slab * 2048 + r * 64 + w0 * 2 + e;
                lXh[idx] = h;
                lXl[idx] = lo;
            }
        }
    }
    __syncthreads();   // xd visible + rot ready

    // ---- GEMM3: mul = xd @ rot, M=32 N=64 K=128 ----
    floatx4 acc3 = zf;
    int wn3 = ng * 16;
    for (int kb = 0; kb < 2; ++kb) {
        #pragma unroll
        for (int kc = 0; kc < 2; ++kc) {
            short8 ah, al, bh, bl;
            ah = frag_ld(lXh + (2 + kb) * 2048, wm + l15, kc, lane);
            al = frag_ld(lXl + (2 + kb) * 2048, wm + l15, kc, lane);
            bh = frag_ld(lWh + kb * 4096, wn3 + l15, kc, lane);
            bl = frag_ld(lWl + kb * 4096, wn3 + l15, kc, lane);
            acc3 = __builtin_amdgcn_mfma_f32_16x16x32_bf16(ah, bh, acc3, 0, 0, 0);
            acc3 = __builtin_amdgcn_mfma_f32_16x16x32_bf16(ah, bl, acc3, 0, 0, 0);
            acc3 = __builtin_amdgcn_mfma_f32_16x16x32_bf16(al, bh, acc3, 0, 0, 0);
        }
    }
    __syncthreads();
    float* lMul = (float*)lXh;
    {
        #pragma unroll
        for (int i = 0; i < 4; i++) {
            int r = wm + r4 + i;
            lMul[r * 65 + wn3 + l15] = acc3[i];
        }
    }
    __syncthreads();

    {   // ---- top-2 argmax over [mul, -mul], margin flag (16 thr/pt) ----
        int p = tid >> 4, q = tid & 15;
        float v1 = -1e30f, v2 = -1e30f; int i1 = 1 << 29;
        #pragma unroll
        for (int j = 0; j < 4; ++j) {
            int c = q * 4 + j;
            if (c < 50) {
                float m = lMul[p * 65 + c];
                float wv, lv; int wi, li;
                if (m >= 0.f) { wv = m; wi = c; lv = -m; li = 50 + c; }
                else          { wv = -m; wi = 50 + c; lv = m; li = c; }
                if (wv > v1 || (wv == v1 && wi < i1)) { v2 = v1; v1 = wv; i1 = wi; }
                else if (wv > v2) v2 = wv;
                if (lv > v1 || (lv == v1 && li < i1)) { v2 = v1; v1 = lv; i1 = li; }
                else if (lv > v2) v2 = lv;
            }
        }
        #pragma unroll
        for (int off = 1; off < 16; off <<= 1) {
            float o1 = __shfl_xor(v1, off, 16);
            int   oi = __shfl_xor(i1, off, 16);
            float o2 = __shfl_xor(v2, off, 16);
            bool take = (o1 > v1) || (o1 == v1 && oi < i1);
            float small = take ? v1 : o1;
            if (take) { v1 = o1; i1 = oi; }
            v2 = fmaxf(fmaxf(v2, o2), small);
        }
        if (q == 0) {
            int pt = base + p;
            bin_out[pt] = i1 + (mski[pt] ? 0 : (NBINS - 1));
            float tau = 3e-4f + 1.5e-3f * v1;
            if (v1 - v2 < tau) {
                int pos = atomicAdd(fixcnt, 1);
                fixlist[pos] = pt;
            }
        }
    }
}

// ---------- fp64 fixup for margin-flagged points ----------
__global__ __launch_bounds__(64) void k_fixup(
    const float* __restrict__ x, const float* __restrict__ g, const float* __restrict__ be,
    const float* __restrict__ w1, const float* __restrict__ b1,
    const float* __restrict__ w2, const float* __restrict__ b2,
    const float* __restrict__ rot, const int* __restrict__ mski,
    const int* __restrict__ fixlist, const int* __restrict__ fixcnt,
    int* __restrict__ bin_out)
{
    __shared__ double xn_s[256];
    __shared__ double h_s[128];
    __shared__ double xd_s[128];
    int lane = threadIdx.x;
    int n = fixcnt[0];
    for (int e = blockIdx.x; e < n; e += gridDim.x) {
        int pt = fixlist[e];
        const float* xr = x + (size_t)pt * FF;
        double s = 0.0, xv[4];
        #pragma unroll
        for (int q = 0; q < 4; q++) { xv[q] = (double)xr[lane + q * 64]; s += xv[q]; }
        #pragma unroll
        for (int off = 1; off < 64; off <<= 1) s += __shfl_xor(s, off, 64);
        double mu = s * (1.0 / 256.0);
        double s2 = 0.0;
        #pragma unroll
        for (int q = 0; q < 4; q++) { double d = xv[q] - mu; s2 += d * d; }
        #pragma unroll
        for (int off = 1; off < 64; off <<= 1) s2 += __shfl_xor(s2, off, 64);
        double rs = 1.0 / sqrt(s2 * (1.0 / 256.0) + 1e-6);
        #pragma unroll
        for (int q = 0; q < 4; q++) {
            int i = lane + q * 64;
            xn_s[i] = (xv[q] - mu) * rs * (double)g[i] + (double)be[i];
        }
        __syncthreads();
        #pragma unroll
        for (int q = 0; q < 2; q++) {
            int j = lane + q * 64;
            double a0 = 0.0, a1 = 0.0;
            for (int k = 0; k < FF; k += 2) {
                a0 += xn_s[k] * (double)w1[k * DDIM + j];
                a1 += xn_s[k + 1] * (double)w1[(k + 1) * DDIM + j];
            }
            double a = (double)b1[j] + a0 + a1;
            h_s[j] = (a > 0.0) ? a : expm1(a);
        }
        __syncthreads();
        #pragma unroll
        for (int q = 0; q < 2; q++) {
            int j = lane + q * 64;
            double a0 = 0.0, a1 = 0.0;
            for (int k = 0; k < DDIM; k += 2) {
                a0 += h_s[k] * (double)w2[k * DDIM + j];
                a1 += h_s[k + 1] * (double)w2[(k + 1) * DDIM + j];
            }
            xd_s[j] = (double)b2[j] + a0 + a1;
        }
        __syncthreads();
        double v; int idx;
        if (lane < NROT) {
            double m = 0.0;
            for (int k = 0; k < DDIM; k++) m += xd_s[k] * (double)rot[k * 100 + lane];
            if (m >= 0.0) { v = m; idx = lane; } else { v = -m; idx = 50 + lane; }
        } else { v = -1e300; idx = 1 << 29; }
        #pragma unroll
        for (int off = 1; off < 64; off <<= 1) {
            double ov = __shfl_xor(v, off, 64);
            int oi = __shfl_xor(idx, off, 64);
            if (ov > v || (ov == v && oi < idx)) { v = ov; idx = oi; }
        }
        if (lane == 0) bin_out[pt] = idx + (mski[pt] ? 0 : (NBINS - 1));
        __syncthreads();
    }
}

// ---------- binning: stable counting sort ----------
__global__ void k_count(const int* __restrict__ bin, int* __restrict__ hist) {
    int c = blockIdx.x % 100, b = blockIdx.x / 100;
    int t = threadIdx.x;
    int v = bin[b * NN + c * BSIZE + t];
    atomicAdd(&hist[(b * 100 + c) * NIDS + v], 1);
}

__global__ void k_offsets(const int* __restrict__ hist, int* __restrict__ offs) {
    __shared__ int tot[NIDS];
    __shared__ int start[NIDS];
    int b = blockIdx.x, v = threadIdx.x;
    if (v < NIDS) {
        int s = 0;
        for (int c = 0; c < 100; c++) s += hist[(b * 100 + c) * NIDS + v];
        tot[v] = s;
    }
    __syncthreads();
    if (threadIdx.x == 0) {
        int run = 0;
        for (int i = 0; i < NIDS; i++) { start[i] = run; run += tot[i]; }
    }
    __syncthreads();
    if (v < NIDS) {
        int run = start[v];
        for (int c = 0; c < 100; c++) {
            offs[(b * 100 + c) * NIDS + v] = run;
            run += hist[(b * 100 + c) * NIDS + v];
        }
    }
}

__global__ void k_scatter(const int* __restrict__ bin, const int* __restrict__ offs,
                          const int* __restrict__ mski, int* __restrict__ flat,
                          float* __restrict__ mf) {
    __shared__ int sv[BSIZE];
    int c = blockIdx.x % 100, b = blockIdx.x / 100;
    int t = threadIdx.x;
    int n = c * BSIZE + t;
    int v = bin[b * NN + n];
    sv[t] = v;
    __syncthreads();
    int rank = 0;
    for (int u = 0; u < t; u++) rank += (sv[u] == v);
    int r = offs[(b * 100 + c) * NIDS + v] + rank;
    flat[b * NN + r] = b * NN + n;
    mf[b * NN + r] = mski[b * NN + n] ? 1.0f : 0.0f;
}

// ---------- k_dm v2: per-bin Gram matrix via split-bf16 MFMA, async gather staging ----------
__global__ __launch_bounds__(512, 4) void k_dm(const ushort* __restrict__ xdh, const ushort* __restrict__ xdl,
                                               const int* __restrict__ flat, const float* __restrict__ mf,
                                               ushort* __restrict__ dmb, float* __restrict__ norm) {
    __shared__ ushort lX[32768];   // Xh slabs at [0),[8192); Xl at [16384),[24576); bounce aliases [0..17408)
    __shared__ float na[128];
    __shared__ float ml[128];
    __shared__ float ps[512];
    int tid = threadIdx.x, lane = tid & 63, wid = tid >> 6;
    int g = blockIdx.x;
    int rowbase = g * 128;
    int l15 = lane & 15;
    int r4 = (lane >> 4) * 4;
    int mg = wid >> 2, ng = wid & 3;
    int wm = mg * 64, wn = ng * 32;
    floatx4 zf = {0.f, 0.f, 0.f, 0.f};

    stage_async(xdh, 128, flat, rowbase, 0, lX, 128, tid);
    stage_async(xdh, 128, flat, rowbase, 64, lX + 8192, 128, tid);
    stage_async(xdl, 128, flat, rowbase, 0, lX + 16384, 128, tid);
    stage_async(xdl, 128, flat, rowbase, 64, lX + 24576, 128, tid);
    if (tid < 128) ml[tid] = mf[rowbase + tid];
    __syncthreads();

    {   // na pass
        int row = tid >> 2, part = tid & 3;
        float s = 0.f;
        #pragma unroll
        for (int kb = 0; kb < 2; ++kb) {
            const ushort* ph = lX + kb * 8192 + row * 64 + part * 16;
            #pragma unroll
            for (int q = 0; q < 2; ++q) {
                uint4 uh = *(const uint4*)(ph + q * 8);
                uint4 ul = *(const uint4*)(ph + 16384 + q * 8);
                const unsigned* wh_ = (const unsigned*)&uh;
                const unsigned* wl_ = (const unsigned*)&ul;
                #pragma unroll
                for (int w = 0; w < 4; ++w) {
                    float x0 = b2f((ushort)(wh_[w] & 0xFFFFu)) + b2f((ushort)(wl_[w] & 0xFFFFu));
                    float x1 = b2f((ushort)(wh_[w] >> 16)) + b2f((ushort)(wl_[w] >> 16));
                    s = fmaf(x0, x0, s);
                    s = fmaf(x1, x1, s);
                }
            }
        }
        s += __shfl_xor(s, 1, 4);
        s += __shfl_xor(s, 2, 4);
        if (part == 0) na[row] = s;
    }

    floatx4 acc[4][2];
    #pragma unroll
    for (int m = 0; m < 4; m++) { acc[m][0] = zf; acc[m][1] = zf; }
    for (int kb = 0; kb < 2; ++kb) {
        #pragma unroll
        for (int kc = 0; kc < 2; ++kc) {
            short8 ah[4], al[4], bh[2], bl[2];
            #pragma unroll
            for (int m = 0; m < 4; m++) {
                ah[m] = frag_ld(lX + kb * 8192, wm + m * 16 + l15, kc, lane);
                al[m] = frag_ld(lX + 16384 + kb * 8192, wm + m * 16 + l15, kc, lane);
            }
            #pragma unroll
            for (int n = 0; n < 2; n++) {
                bh[n] = frag_ld(lX + kb * 8192, wn + n * 16 + l15, kc, lane);
                bl[n] = frag_ld(lX + 16384 + kb * 8192, wn + n * 16 + l15, kc, lane);
            }
            #pragma unroll
            for (int m = 0; m < 4; m++)
                #pragma unroll
                for (int n = 0; n < 2; n++) {
                    acc[m][n] = __builtin_amdgcn_mfma_f32_16x16x32_bf16(ah[m], bh[n], acc[m][n], 0, 0, 0);
                    acc[m][n] = __builtin_amdgcn_mfma_f32_16x16x32_bf16(ah[m], bl[n], acc[m][n], 0, 0, 0);
                    acc[m][n] = __builtin_amdgcn_mfma_f32_16x16x32_bf16(al[m], bh[n], acc[m][n], 0, 0, 0);
                }
        }
    }
    __syncthreads();

    ushort* Ls = lX;
    for (int m = 0; m < 4; ++m) {
        int r0 = wm + m * 16 + r4;
        float rs[4] = {0.f, 0.f, 0.f, 0.f};
        #pragma unroll
        for (int n = 0; n < 2; ++n) {
            int c = wn + n * 16 + l15;
            float nac = na[c], mlc = ml[c];
            #pragma unroll
            for (int i = 0; i < 4; ++i) {
                int r = r0 + i;
                float D2 = na[r] - 2.f * acc[m][n][i] + nac;
                float dv = expf(-0.1f * sqrtf(fmaxf(D2, 1e-6f)));
                dv *= ml[r] * mlc;
                rs[i] += dv;
                Ls[r * 136 + c] = f2b(dv);
            }
        }
        #pragma unroll
        for (int off = 1; off < 16; off <<= 1) {
            #pragma unroll
            for (int i = 0; i < 4; ++i) rs[i] += __shfl_xor(rs[i], off, 16);
        }
        if (l15 == 0) {
            #pragma unroll
            for (int i = 0; i < 4; ++i) ps[(r0 + i) * 4 + ng] = rs[i];
        }
    }
    __syncthreads();

    #pragma unroll
    for (int it = 0; it < 4; ++it) {
        int gi = it * 512 + tid;
        int row = gi >> 4, ch = gi & 15;
        uint4 v = *(const uint4*)(Ls + row * 136 + ch * 8);
        *(uint4*)(dmb + (size_t)g * 16384 + row * 128 + ch * 8) = v;
    }
    if (tid < 128) {
        float deg = ps[tid * 4 + 0] + ps[tid * 4 + 1] + ps[tid * 4 + 2] + ps[tid * 4 + 3];
        deg = fminf(deg, 1000.0f);
        norm[rowbase + tid] = (1.0f / sqrtf(deg + 1e-6f)) * ml[tid];
    }
}

// ---------- fused per-layer graph conv v2: merged triple GEMM, 80KB LDS, 2 blocks/CU ----------
// 1-D grid 3200 with XCD-locality remap.
template<int LAYER>
__global__ __launch_bounds__(512, 4) void k_layer(
    const ushort* __restrict__ A, const int* __restrict__ rowmap,
    const ushort* __restrict__ ThT, const ushort* __restrict__ WhT, const ushort* __restrict__ WtT,
    const float* __restrict__ bt, const ushort* __restrict__ dmb,
    const float* __restrict__ norm, const float* __restrict__ mf,
    ushort* __restrict__ outb, float* __restrict__ outf, const int* __restrict__ flatscat)
{
    __shared__ char smem[81920];
    ushort* lAbuf = (ushort*)smem;                 // 2 x 16KB A ping
    ushort* lB    = (ushort*)(smem + 32768);       // 6 x 8KB: th0 th1 wh0 wh1 wt0 wt1
    ushort* lT    = (ushort*)smem;                 // post-GEMM: 2 x 8KB T^T j-slabs
    ushort* ldm   = (ushort*)(smem + 32768);       // post-GEMM: 2 x 16KB dm slabs

    int tid = threadIdx.x, lane = tid & 63, wid = tid >> 6;
    int bid = blockIdx.x;
    int grp = bid >> 5, within = bid & 31;
    int nh = within >> 3, g = grp * 8 + (within & 7);
    int rowbase = g * 128, nbase = nh * 64;
    int l15 = lane & 15;
    int r4 = (lane >> 4) * 4;
    int wm = (wid >> 1) * 32, wn = (wid & 1) * 32;
    const ushort* dmg = dmb + (size_t)g * 16384;
    floatx4 zf = {0.f, 0.f, 0.f, 0.f};

    stage_async(A, 256, rowmap, rowbase, 0, lAbuf, 128, tid);
    stage_async(ThT, 256, nullptr, nbase, 0, lB + 0 * 4096, 64, tid);
    stage_async(WhT, 256, nullptr, nbase, 0, lB + 2 * 4096, 64, tid);
    stage_async(WtT, 256, nullptr, nbase, 0, lB + 4 * 4096, 64, tid);
    __syncthreads();

    floatx4 accT[2][2], accH[2][2], accG[2][2];
    #pragma unroll
    for (int m = 0; m < 2; m++)
        #pragma unroll
        for (int n = 0; n < 2; n++) { accT[m][n] = zf; accH[m][n] = zf; accG[m][n] = zf; }
    for (int kb = 0; kb < 4; ++kb) {
        if (kb < 3) {
            int pp = (kb + 1) & 1;
            stage_async(A, 256, rowmap, rowbase, (size_t)(kb + 1) * 64, lAbuf + pp * 8192, 128, tid);
            stage_async(ThT, 256, nullptr, nbase, (size_t)(kb + 1) * 64, lB + (0 + pp) * 4096, 64, tid);
            stage_async(WhT, 256, nullptr, nbase, (size_t)(kb + 1) * 64, lB + (2 + pp) * 4096, 64, tid);
            stage_async(WtT, 256, nullptr, nbase, (size_t)(kb + 1) * 64, lB + (4 + pp) * 4096, 64, tid);
        }
        const ushort* lA = lAbuf + (kb & 1) * 8192;
        const ushort* sTh = lB + (0 + (kb & 1)) * 4096;
        const ushort* sWh = lB + (2 + (kb & 1)) * 4096;
        const ushort* sWt = lB + (4 + (kb & 1)) * 4096;
        #pragma unroll
        for (int kc = 0; kc < 2; ++kc) {
            short8 a[2], bt_[2], bh_[2], bg_[2];
            #pragma unroll
            for (int m = 0; m < 2; m++) a[m] = frag_ld(lA, wm + m * 16 + l15, kc, lane);
            #pragma unroll
            for (int n = 0; n < 2; n++) {
                bt_[n] = frag_ld(sTh, wn + n * 16 + l15, kc, lane);
                bh_[n] = frag_ld(sWh, wn + n * 16 + l15, kc, lane);
                bg_[n] = frag_ld(sWt, wn + n * 16 + l15, kc, lane);
            }
            #pragma unroll
            for (int m = 0; m < 2; m++)
                #pragma unroll
                for (int n = 0; n < 2; n++) {
                    accT[m][n] = __builtin_amdgcn_mfma_f32_16x16x32_bf16(a[m], bt_[n], accT[m][n], 0, 0, 0);
                    accH[m][n] = __builtin_amdgcn_mfma_f32_16x16x32_bf16(a[m], bh_[n], accH[m][n], 0, 0, 0);
                    accG[m][n] = __builtin_amdgcn_mfma_f32_16x16x32_bf16(a[m], bg_[n], accG[m][n], 0, 0, 0);
                }
        }
        __syncthreads();
    }

    stage_async(dmg, 128, nullptr, 0, 0, ldm, 128, tid);
    stage_async(dmg, 128, nullptr, 0, 64, ldm + 8192, 128, tid);

    {   // T^T (scaled by norm, bf16, frag-swizzled) into lT j-slabs
        #pragma unroll
        for (int m = 0; m < 2; m++) {
            float4 nv = *(const float4*)(norm + rowbase + wm + m * 16 + r4);
            float nvv[4] = {nv.x, nv.y, nv.z, nv.w};
            int jloc0 = wm + m * 16 + r4;
            int jb = jloc0 >> 6, jj = jloc0 & 63;
            #pragma unroll
            for (int n = 0; n < 2; n++) {
                int cloc = wn + n * 16 + l15;
                char* bp = (char*)(lT + jb * 4096) + cloc * 128;
                int cx = (cloc & 7) << 2;
                ushort t0 = f2b(accT[m][n][0] * nvv[0]);
                ushort t1 = f2b(accT[m][n][1] * nvv[1]);
                ushort t2 = f2b(accT[m][n][2] * nvv[2]);
                ushort t3 = f2b(accT[m][n][3] * nvv[3]);
                *(unsigned*)(bp + ((((jj >> 1) + 0) ^ cx) << 2)) = (unsigned)t0 | ((unsigned)t1 << 16);
                *(unsigned*)(bp + ((((jj >> 1) + 1) ^ cx) << 2)) = (unsigned)t2 | ((unsigned)t3 << 16);
            }
        }
    }
    __syncthreads();

    floatx4 accFH[2][2];
    #pragma unroll
    for (int m = 0; m < 2; m++) { accFH[m][0] = zf; accFH[m][1] = zf; }
    for (int kb = 0; kb < 2; ++kb) {
        #pragma unroll
        for (int kc = 0; kc < 2; ++kc) {
            short8 a[2], b[2];
            #pragma unroll
            for (int m = 0; m < 2; m++) a[m] = frag_ld(ldm + kb * 8192, wm + m * 16 + l15, kc, lane);
            #pragma unroll
            for (int n = 0; n < 2; n++) b[n] = frag_ld(lT + kb * 4096, wn + n * 16 + l15, kc, lane);
            #pragma unroll
            for (int m = 0; m < 2; m++)
                #pragma unroll
                for (int n = 0; n < 2; n++)
                    accFH[m][n] = __builtin_amdgcn_mfma_f32_16x16x32_bf16(a[m], b[n], accFH[m][n], 0, 0, 0);
        }
    }
    __syncthreads();

    for (int m = 0; m < 2; m++) {
        int r0l = wm + m * 16 + r4;
        int r0g = rowbase + r0l;
        float4 mv = *(const float4*)(mf + r0g);
        float4 nv = *(const float4*)(norm + r0g);
        float mvv[4] = {mv.x, mv.y, mv.z, mv.w};
        float nvv[4] = {nv.x, nv.y, nv.z, nv.w};
        float vals[2][4];
        #pragma unroll
        for (int n = 0; n < 2; n++) {
            int cg = nbase + wn + n * 16 + l15;
            float btc = bt[cg];
            #pragma unroll
            for (int i = 0; i < 4; i++) {
                float gate = 1.f / (1.f + expf(-(accG[m][n][i] + btc)));
                float fh = accFH[m][n][i] * nvv[i];
                float het = mvv[i] * accH[m][n][i];
                float o = gate * fh + (1.f - gate) * het;
                o = (o > 0.f) ? o : expm1f(o);
                vals[n][i] = o * mvv[i];
            }
        }
        if (LAYER == 0) {
            ushort* Ls = (ushort*)smem;
            int bbase = wid * 512;
            #pragma unroll
            for (int n = 0; n < 2; n++)
                #pragma unroll
                for (int i = 0; i < 4; i++)
                    Ls[bbase + (r4 + i) * 32 + n * 16 + l15] = f2b(vals[n][i]);
            __builtin_amdgcn_s_waitcnt(0);
            #pragma unroll
            for (int it = 0; it < 2; ++it) {
                int lr = (lane >> 3) + it * 8;
                int lc4 = (lane & 7) * 4;
                ushort4 tv = *(const ushort4*)(Ls + bbase + lr * 32 + lc4);
                int rg = rowbase + wm + m * 16 + lr;
                *(ushort4*)(outb + (size_t)rg * 256 + nbase + wn + lc4) = tv;
            }
        } else {
            float* Ls = (float*)smem;
            int bbase = wid * 512;
            #pragma unroll
            for (int n = 0; n < 2; n++)
                #pragma unroll
                for (int i = 0; i < 4; i++)
                    Ls[bbase + (r4 + i) * 32 + n * 16 + l15] = vals[n][i];
            __builtin_amdgcn_s_waitcnt(0);
            #pragma unroll
            for (int it = 0; it < 2; ++it) {
                int lr = (lane >> 3) + it * 8;
                int lc4 = (lane & 7) * 4;
                float4 tv = *(const float4*)(Ls + bbase + lr * 32 + lc4);
                int rg = rowbase + wm + m * 16 + lr;
                int dst = flatscat[rg];
                *(float4*)(outf + (size_t)dst * 256 + nbase + wn + lc4) = tv;
            }
        }
    }
}

extern "C" void kernel_launch(void* const* d_in, const int* in_sizes, int n_in,
                              void* d_out, int out_size, void* d_ws, size_t ws_size,
                              hipStream_t stream) {
    const float* x    = (const float*)d_in[0];
    const void*  msk  = d_in[1];
    const float* ln_g = (const float*)d_in[2];
    const float* ln_b = (const float*)d_in[3];
    const float* w1   = (const float*)d_in[4];
    const float* b1   = (const float*)d_in[5];
    const float* w2   = (const float*)d_in[6];
    const float* b2   = (const float*)d_in[7];
    const float* rot  = (const float*)d_in[8];
    const float* th0  = (const float*)d_in[9];
    const float* wh0  = (const float*)d_in[10];
    const float* wt0  = (const float*)d_in[11];
    const float* bt0  = (const float*)d_in[12];
    const float* th1  = (const float*)d_in[13];
    const float* wh1  = (const float*)d_in[14];
    const float* wt1  = (const float*)d_in[15];
    const float* bt1  = (const float*)d_in[16];

    char* ws = (char*)d_ws;
    ushort* out0 = (ushort*)(ws + OFF_OUT0);
    ushort* dmb  = (ushort*)(ws + OFF_DMB);
    ushort* wb   = (ushort*)(ws + OFF_WB);
    ushort* wbth0 = wb + 0 * 65536;
    ushort* wbwh0 = wb + 1 * 65536;
    ushort* wbwt0 = wb + 2 * 65536;
    ushort* wbth1 = wb + 3 * 65536;
    ushort* wbwh1 = wb + 4 * 65536;
    ushort* wbwt1 = wb + 5 * 65536;
    float* norm = (float*)(ws + OFF_NORM);
    float* mf   = (float*)(ws + OFF_MF);
    int*   bin  = (int*)(ws + OFF_BIN);
    int*   flat = (int*)(ws + OFF_FLAT);
    int*   mski = (int*)(ws + OFF_MSKI);
    int*   hist = (int*)(ws + OFF_HIST);
    int*   offs = (int*)(ws + OFF_OFFS);
    int*   flag = (int*)(ws + OFF_FLAG);
    int*   fixcnt = (int*)(ws + OFF_CNT);
    int*   fixlist = (int*)(ws + OFF_LIST);
    ushort* w1h = (ushort*)(ws + OFF_W1H);
    ushort* w1l = (ushort*)(ws + OFF_W1L);
    ushort* w2h = (ushort*)(ws + OFF_W2H);
    ushort* w2l = (ushort*)(ws + OFF_W2L);
    ushort* rth = (ushort*)(ws + OFF_RH);
    ushort* rtl = (ushort*)(ws + OFF_RL);
    ushort* xdh = (ushort*)d_out;
    ushort* xdl = xdh + (size_t)PTS * DDIM;
    ushort* xnb = (ushort*)((char*)d_out + (size_t)PTS * DDIM * 4);

    hipMemsetAsync(hist, 0, HISTBYTES, stream);
    hipMemsetAsync(fixcnt, 0, 4, stream);
    k_maskflag<<<1, 256, 0, stream>>>((const int*)msk, flag);
    k_masknorm<<<PTS / 256, 256, 0, stream>>>(msk, flag, mski);
    k_wprep<<<dim3(16, 6), 256, 0, stream>>>(th0, wh0, wt0, th1, wh1, wt1,
                                             wbth0, wbwh0, wbwt0, wbth1, wbwh1, wbwt1);
    k_wsplit<<<8, 256, 0, stream>>>(w1, 256, 128, 128, 128, w1h, w1l);
    k_wsplit<<<4, 256, 0, stream>>>(w2, 128, 128, 128, 128, w2h, w2l);
    k_wsplit<<<2, 256, 0, stream>>>(rot, 128, 64, 100, 50, rth, rtl);
    k_stage1<<<PTS / 32, 512, 0, stream>>>(x, ln_g, ln_b, b1, b2,
                                           w1h, w1l, w2h, w2l, rth, rtl, mski,
                                           xnb, xdh, xdl, bin, fixlist, fixcnt);
    k_fixup<<<4096, 64, 0, stream>>>(x, ln_g, ln_b, w1, b1, w2, b2, rot, mski,
                                     fixlist, fixcnt, bin);
    k_count<<<800, 128, 0, stream>>>(bin, hist);
    k_offsets<<<8, 256, 0, stream>>>(hist, offs);
    k_scatter<<<800, 128, 0, stream>>>(bin, offs, mski, flat, mf);
    k_dm<<<800, 512, 0, stream>>>(xdh, xdl, flat, mf, dmb, norm);
    // layer 0 (fused, XCD-locality remapped 1-D grid)
    k_layer<0><<<3200, 512, 0, stream>>>(xnb, flat, wbth0, wbwh0, wbwt0, bt0,
                                         dmb, norm, mf, out0, nullptr, nullptr);
    // layer 1 (fused, scattered fp32 output)
    k_layer<1><<<3200, 512, 0, stream>>>(out0, nullptr, wbth1, wbwh1, wbwt1, bt1,
                                         dmb, norm, mf, nullptr, (float*)d_out, flat);
}